// Round 1
// baseline (2329.903 us; speedup 1.0000x reference)
//
#include <hip/hip_runtime.h>
#include <hip/hip_bf16.h>
#include <math.h>

#define D 2048
#define NROWS 2048      // b*n
#define H 16
#define DH 128
#define CHK 64
#define NC 16
#define EPSC 1e-6f
#define RSQDH 0.08838834764831845f   // 128^-0.5

// ---------------- fp32 tiled GEMM: C[M,N] = A[M,K] @ B[K,N] ----------------
__global__ __launch_bounds__(256) void gemm_f32(const float* __restrict__ A,
                                                const float* __restrict__ B,
                                                float* __restrict__ C,
                                                int M, int N, int K) {
  __shared__ float As[128][17];
  __shared__ float Bs[16][128];
  const int tid = threadIdx.x;
  const int tx = tid & 15, ty = tid >> 4;
  const int row0 = blockIdx.y * 128, col0 = blockIdx.x * 128;
  float acc[8][8] = {};
  for (int k0 = 0; k0 < K; k0 += 16) {
#pragma unroll
    for (int i = 0; i < 2; i++) {
      int idx = tid + i * 256;
      int r = idx >> 2, c4 = (idx & 3) * 4;
      float4 av = *(const float4*)(A + (size_t)(row0 + r) * K + k0 + c4);
      As[r][c4 + 0] = av.x; As[r][c4 + 1] = av.y;
      As[r][c4 + 2] = av.z; As[r][c4 + 3] = av.w;
    }
#pragma unroll
    for (int i = 0; i < 2; i++) {
      int idx = tid + i * 256;
      int r = idx >> 5, c4 = (idx & 31) * 4;
      *(float4*)&Bs[r][c4] = *(const float4*)(B + (size_t)(k0 + r) * N + col0 + c4);
    }
    __syncthreads();
#pragma unroll
    for (int kk = 0; kk < 16; kk++) {
      float a[8], bb[8];
#pragma unroll
      for (int i = 0; i < 8; i++) a[i] = As[ty * 8 + i][kk];
      *(float4*)&bb[0] = *(float4*)&Bs[kk][tx * 8];
      *(float4*)&bb[4] = *(float4*)&Bs[kk][tx * 8 + 4];
#pragma unroll
      for (int i = 0; i < 8; i++)
#pragma unroll
        for (int j = 0; j < 8; j++) acc[i][j] += a[i] * bb[j];
    }
    __syncthreads();
  }
#pragma unroll
  for (int i = 0; i < 8; i++) {
    float4 v0 = {acc[i][0], acc[i][1], acc[i][2], acc[i][3]};
    float4 v1 = {acc[i][4], acc[i][5], acc[i][6], acc[i][7]};
    *(float4*)(C + (size_t)(row0 + ty * 8 + i) * N + col0 + tx * 8) = v0;
    *(float4*)(C + (size_t)(row0 + ty * 8 + i) * N + col0 + tx * 8 + 4) = v1;
  }
}

// ---------------- activations: softmax/clip q,k ; gate g ; kb, vb ----------
__device__ __forceinline__ float gate_fn(float z) {
  float t = -z;
  float sp = (t > 20.f) ? t : log1pf(expf(t));   // softplus(-z)
  float g = -sp * (1.f / 16.f);                  // log_sigmoid(z)/16
  return fminf(fmaxf(g, -16.f), 16.f);
}

__global__ __launch_bounds__(256) void act_kernel(const float* __restrict__ qr,
                                                  const float* __restrict__ kr,
                                                  const float* __restrict__ vr,
                                                  float* __restrict__ qs,
                                                  float* __restrict__ ksm,
                                                  float* __restrict__ kb,
                                                  float* __restrict__ vb) {
  int wave = blockIdx.x * 4 + (threadIdx.x >> 6);  // (row*16 + h)
  int lane = threadIdx.x & 63;
  size_t base = (size_t)wave * 128;
  float q0 = qr[base + lane], q1 = qr[base + 64 + lane];
  float k0 = kr[base + lane], k1 = kr[base + 64 + lane];
  float v0 = vr[base + lane], v1 = vr[base + 64 + lane];

  // softmax(q) over 128
  float m = fmaxf(q0, q1);
  for (int o = 1; o < 64; o <<= 1) m = fmaxf(m, __shfl_xor(m, o));
  float e0 = expf(q0 - m), e1 = expf(q1 - m);
  float s = e0 + e1;
  for (int o = 1; o < 64; o <<= 1) s += __shfl_xor(s, o);
  float inv = 1.f / s;
  float qs0 = fminf(fmaxf(e0 * inv, EPSC), 1.f - EPSC) * RSQDH;
  float qs1 = fminf(fmaxf(e1 * inv, EPSC), 1.f - EPSC) * RSQDH;

  // softmax(k) over 128
  float mk = fmaxf(k0, k1);
  for (int o = 1; o < 64; o <<= 1) mk = fmaxf(mk, __shfl_xor(mk, o));
  float f0 = expf(k0 - mk), f1 = expf(k1 - mk);
  float sk = f0 + f1;
  for (int o = 1; o < 64; o <<= 1) sk += __shfl_xor(sk, o);
  float invk = 1.f / sk;
  float ks0 = fminf(fmaxf(f0 * invk, EPSC), 1.f - EPSC);
  float ks1 = fminf(fmaxf(f1 * invk, EPSC), 1.f - EPSC);

  float g0 = gate_fn(k0), g1 = gate_fn(k1);

  qs[base + lane] = qs0;        qs[base + 64 + lane] = qs1;
  ksm[base + lane] = ks0;       ksm[base + 64 + lane] = ks1;
  kb[base + lane] = ks0 * g0;   kb[base + 64 + lane] = ks1 * g1;
  vb[base + lane] = v0 * g0;    vb[base + 64 + lane] = v1 * g1;
}

// ------- per-chunk: L, attn_pre, forward substitution -> u, w --------------
__global__ __launch_bounds__(256) void chunk_uw_kernel(const float* __restrict__ qs,
                                                       const float* __restrict__ ksm,
                                                       const float* __restrict__ kb,
                                                       const float* __restrict__ vb,
                                                       float* __restrict__ u,
                                                       float* __restrict__ w,
                                                       float* __restrict__ attn) {
  __shared__ float smem[16384];          // 64KB
  float* k_s = smem;                     // [64][128]
  float* kb_s = smem + 8192;             // [64][128]
  const int tid = threadIdx.x;
  const int bh = blockIdx.x >> 4, ci = blockIdx.x & 15;
  const int rowbase = (bh >> 4) * 1024 + ci * 64;
  const int colbase = (bh & 15) * 128;

  for (int i = 0; i < 32; i++) {
    int idx = tid + i * 256;
    int r = idx >> 7, c = idx & 127;
    size_t g = (size_t)(rowbase + r) * D + colbase + c;
    k_s[idx] = ksm[g];
    kb_s[idx] = kb[g];
  }
  __syncthreads();

  float Lreg[16];
  for (int sIt = 0; sIt < 16; sIt++) {
    int e = tid + sIt * 256;             // 0..4095
    int i = e >> 6, j = e & 63;
    float accL = 0.f, accA = 0.f;
    const float* qrow = qs + (size_t)(rowbase + i) * D + colbase;
    for (int cc = 0; cc < 128; cc++) {
      int c = (cc + tid) & 127;          // rotate to avoid bank conflicts
      float kj = k_s[j * 128 + c];
      accL += kb_s[i * 128 + c] * kj;
      accA += qrow[c] * kj;
    }
    Lreg[sIt] = (j < i) ? accL : 0.f;
    attn[(size_t)blockIdx.x * 4096 + e] = (j <= i) ? accA : 0.f;
  }
  __syncthreads();
  float* L_s = smem;                     // overwrite k_s with L (64x64)
  for (int sIt = 0; sIt < 16; sIt++) L_s[tid + sIt * 256] = Lreg[sIt];
  __syncthreads();

  // forward substitution: (I+L) x = rhs ; threads 0..127 -> u cols, 128..255 -> w cols
  float x[64];
  const int c = tid & 127;
  const bool isU = (tid < 128);
  if (isU) {
#pragma unroll
    for (int j = 0; j < 64; j++) x[j] = vb[(size_t)(rowbase + j) * D + colbase + c];
  } else {
#pragma unroll
    for (int j = 0; j < 64; j++) x[j] = kb_s[j * 128 + c];
  }
#pragma unroll
  for (int i = 0; i < 64; i++) {
    float xi = x[i];
#pragma unroll
    for (int r = i + 1; r < 64; r++) x[r] -= L_s[r * 64 + i] * xi;
  }
  float* dst = isU ? u : w;
#pragma unroll
  for (int j = 0; j < 64; j++) dst[(size_t)(rowbase + j) * D + colbase + c] = x[j];
}

// ---------------- sequential scan over chunks (per b,h and dv-quarter) ----
__global__ __launch_bounds__(256) void scan_kernel(const float* __restrict__ qs,
                                                   const float* __restrict__ ksm,
                                                   const float* __restrict__ u,
                                                   const float* __restrict__ w,
                                                   const float* __restrict__ attn,
                                                   float* __restrict__ o_lin) {
  __shared__ float S_s[128 * 32];   // S[k][c]
  __shared__ float u_s[64 * 32];    // u'[i][c]
  __shared__ float st[64 * 128];    // staging for w/q/k chunk
  const int tid = threadIdx.x;
  const int bh = blockIdx.x;
  const int b = bh >> 4, h = bh & 15;
  const int g = blockIdx.y;
  const int colbase = h * 128;
  const int vcol = h * 128 + g * 32;
  for (int i = tid; i < 4096; i += 256) S_s[i] = 0.f;
  const int cc = tid & 31;
  const int ig = tid >> 5;
  const int i0 = ig * 8;
  const int k0 = ig * 16;

  for (int chunk = 0; chunk < 16; chunk++) {
    const int rowbase = b * 1024 + chunk * 64;
    const size_t gbase = (size_t)rowbase * D;
    __syncthreads();
    for (int idx = tid; idx < 8192; idx += 256)
      st[idx] = w[gbase + (size_t)(idx >> 7) * D + colbase + (idx & 127)];
    __syncthreads();
    // phase1: u' = u - w @ S
    {
      float acc[8] = {};
      for (int k = 0; k < 128; k++) {
        float sv = S_s[k * 32 + cc];
#pragma unroll
        for (int r = 0; r < 8; r++) acc[r] += st[(i0 + r) * 128 + k] * sv;
      }
#pragma unroll
      for (int r = 0; r < 8; r++) {
        float up = u[gbase + (size_t)(i0 + r) * D + vcol + cc] - acc[r];
        u_s[(i0 + r) * 32 + cc] = up;
      }
    }
    __syncthreads();
    for (int idx = tid; idx < 8192; idx += 256)
      st[idx] = qs[gbase + (size_t)(idx >> 7) * D + colbase + (idx & 127)];
    __syncthreads();
    // phase2: o = q@S + attn@u'
    {
      float acc[8] = {};
      for (int k = 0; k < 128; k++) {
        float sv = S_s[k * 32 + cc];
#pragma unroll
        for (int r = 0; r < 8; r++) acc[r] += st[(i0 + r) * 128 + k] * sv;
      }
      const float* ab = attn + (size_t)(bh * 16 + chunk) * 4096;
      for (int j = 0; j < 64; j++) {
        float uv = u_s[j * 32 + cc];
#pragma unroll
        for (int r = 0; r < 8; r++) acc[r] += ab[(i0 + r) * 64 + j] * uv;
      }
#pragma unroll
      for (int r = 0; r < 8; r++)
        o_lin[gbase + (size_t)(i0 + r) * D + vcol + cc] = acc[r];
    }
    __syncthreads();
    for (int idx = tid; idx < 8192; idx += 256)
      st[idx] = ksm[gbase + (size_t)(idx >> 7) * D + colbase + (idx & 127)];
    __syncthreads();
    // phase3: S += k^T @ u'
    {
      float acc[16] = {};
      for (int i = 0; i < 64; i++) {
        float uv = u_s[i * 32 + cc];
#pragma unroll
        for (int kk = 0; kk < 16; kk++) acc[kk] += st[i * 128 + k0 + kk] * uv;
      }
#pragma unroll
      for (int kk = 0; kk < 16; kk++) S_s[(k0 + kk) * 32 + cc] += acc[kk];
    }
  }
}

// ---------------- base causal softmax attention + 0.5/0.5 mix -------------
__global__ __launch_bounds__(256) void base_attn_kernel(const float* __restrict__ qr,
                                                        const float* __restrict__ kr,
                                                        const float* __restrict__ vr,
                                                        const float* __restrict__ o_lin,
                                                        float* __restrict__ mixb) {
  __shared__ float q_s[64 * 128];
  __shared__ float kv_s[64 * 128];
  const int tid = threadIdx.x;
  const int bh = blockIdx.x;
  const int b = bh >> 4, h = bh & 15;
  const int qt = blockIdx.y;
  const int lane = tid & 63, wv = tid >> 6;
  const int rloc = wv * 16 + (lane >> 2);
  const int dsb = (lane & 3) * 32;
  const size_t qrow0 = (size_t)(b * 1024 + qt * 64);

  for (int idx = tid; idx < 8192; idx += 256)
    q_s[idx] = qr[(qrow0 + (idx >> 7)) * D + h * 128 + (idx & 127)];

  float o[32] = {};
  float m = -INFINITY, l = 0.f;
  float s[64];
  const int qg = qt * 64 + rloc;

  for (int kt = 0; kt <= qt; kt++) {
    const size_t krow0 = (size_t)(b * 1024 + kt * 64);
    __syncthreads();
    for (int idx = tid; idx < 8192; idx += 256)
      kv_s[idx] = kr[(krow0 + (idx >> 7)) * D + h * 128 + (idx & 127)];
    __syncthreads();
#pragma unroll
    for (int j = 0; j < 64; j++) {
      float p = 0.f;
#pragma unroll
      for (int c2 = 0; c2 < 32; c2++) {
        int pc = (c2 + lane) & 31;
        p += q_s[rloc * 128 + dsb + pc] * kv_s[j * 128 + dsb + pc];
      }
      p += __shfl_xor(p, 1);
      p += __shfl_xor(p, 2);
      int kg = kt * 64 + j;
      s[j] = (kg <= qg) ? p * RSQDH : -INFINITY;
    }
    float mt = s[0];
#pragma unroll
    for (int j = 1; j < 64; j++) mt = fmaxf(mt, s[j]);
    float mn = fmaxf(m, mt);
    float f = expf(m - mn);
    l *= f;
#pragma unroll
    for (int c2 = 0; c2 < 32; c2++) o[c2] *= f;
    m = mn;
    __syncthreads();
    for (int idx = tid; idx < 8192; idx += 256)
      kv_s[idx] = vr[(krow0 + (idx >> 7)) * D + h * 128 + (idx & 127)];
    __syncthreads();
#pragma unroll
    for (int j = 0; j < 64; j++) {
      float p = expf(s[j] - mn);
      l += p;
#pragma unroll
      for (int c2 = 0; c2 < 32; c2++) {
        int pc = (c2 + lane) & 31;
        o[c2] += p * kv_s[j * 128 + dsb + pc];
      }
    }
  }
  float invl = 1.f / l;
#pragma unroll
  for (int c2 = 0; c2 < 32; c2++) {
    int pc = (c2 + lane) & 31;
    size_t off = (qrow0 + rloc) * D + h * 128 + dsb + pc;
    mixb[off] = 0.5f * (o[c2] * invl) + 0.5f * o_lin[off];
  }
}

// ---------------------------------------------------------------------------
extern "C" void kernel_launch(void* const* d_in, const int* in_sizes, int n_in,
                              void* d_out, int out_size, void* d_ws, size_t ws_size,
                              hipStream_t stream) {
  const float* x  = (const float*)d_in[0];
  const float* Wq = (const float*)d_in[1];
  const float* Wk = (const float*)d_in[2];
  const float* Wv = (const float*)d_in[3];
  const float* Wo = (const float*)d_in[4];
  float* out = (float*)d_out;
  float* ws = (float*)d_ws;

  const size_t B = (size_t)NROWS * D;   // 4,194,304 floats
  float* q_raw = ws + 0 * B;
  float* k_raw = ws + 1 * B;
  float* v_raw = ws + 2 * B;
  float* q_s   = ws + 3 * B;
  float* k_sm  = ws + 4 * B;
  float* kb    = ws + 5 * B;
  float* vb    = ws + 6 * B;
  float* u     = ws + 7 * B;
  float* w     = ws + 8 * B;
  float* attn  = ws + 9 * B;            // 2,097,152 floats
  float* o_lin = kb;                    // reuse (kb dead after chunk_uw)
  float* mixb  = vb;                    // reuse (vb dead after chunk_uw)

  dim3 gg(16, 16);
  gemm_f32<<<gg, 256, 0, stream>>>(x, Wq, q_raw, NROWS, D, D);
  gemm_f32<<<gg, 256, 0, stream>>>(x, Wk, k_raw, NROWS, D, D);
  gemm_f32<<<gg, 256, 0, stream>>>(x, Wv, v_raw, NROWS, D, D);
  act_kernel<<<8192, 256, 0, stream>>>(q_raw, k_raw, v_raw, q_s, k_sm, kb, vb);
  chunk_uw_kernel<<<512, 256, 0, stream>>>(q_s, k_sm, kb, vb, u, w, attn);
  scan_kernel<<<dim3(32, 4), 256, 0, stream>>>(q_s, k_sm, u, w, attn, o_lin);
  base_attn_kernel<<<dim3(32, 16), 256, 0, stream>>>(q_raw, k_raw, v_raw, o_lin, mixb);
  gemm_f32<<<gg, 256, 0, stream>>>(mixb, Wo, out, NROWS, D, D);
}

// Round 2
// 1035.432 us; speedup vs baseline: 2.2502x; 2.2502x over previous
//
#include <hip/hip_runtime.h>
#include <hip/hip_bf16.h>
#include <math.h>

#define D 2048
#define NROWS 2048      // b*n
#define H 16
#define DH 128
#define CHK 64
#define NC 16
#define EPSC 1e-6f
#define RSQDH 0.08838834764831845f   // 128^-0.5

typedef unsigned short ushort_t;
typedef __attribute__((ext_vector_type(4))) float f4_t;
typedef __attribute__((ext_vector_type(8))) short s8_t;
typedef __attribute__((ext_vector_type(4))) unsigned short us4_t;

#define MFMA16(a, b, c) __builtin_amdgcn_mfma_f32_16x16x32_bf16((a), (b), (c), 0, 0, 0)
#define GLOAD16(g, l) __builtin_amdgcn_global_load_lds((const __attribute__((address_space(1))) unsigned int*)(g), (__attribute__((address_space(3))) unsigned int*)(l), 16, 0, 0)

__device__ __forceinline__ ushort_t f2bf(float f) {
  union { float f; unsigned u; } v; v.f = f;
  unsigned r = (v.u + 0x7fffu + ((v.u >> 16) & 1u)) >> 16;
  return (ushort_t)r;
}
__device__ __forceinline__ float bf2f(ushort_t h) {
  union { unsigned u; float f; } v; v.u = ((unsigned)h) << 16;
  return v.f;
}

// ---------------- split fp32 -> bf16 hi/lo (elementwise) -------------------
__global__ __launch_bounds__(256) void split_f32(const float* __restrict__ in,
                                                 ushort_t* __restrict__ hi,
                                                 ushort_t* __restrict__ lo) {
  int i = (blockIdx.x * 256 + threadIdx.x) * 4;
  float4 v = *(const float4*)(in + i);
  us4_t h, l;
  float vv[4] = {v.x, v.y, v.z, v.w};
#pragma unroll
  for (int j = 0; j < 4; j++) {
    ushort_t hb = f2bf(vv[j]);
    h[j] = hb;
    l[j] = f2bf(vv[j] - bf2f(hb));
  }
  *(us4_t*)(hi + i) = h;
  *(us4_t*)(lo + i) = l;
}

// ------------- weight: transpose + split -> Wt_hi[n][k], Wt_lo[n][k] -------
__global__ __launch_bounds__(256) void wsplit_t(const float* __restrict__ W,
                                                ushort_t* __restrict__ Th,
                                                ushort_t* __restrict__ Tl) {
  __shared__ float t[32][33];
  const int tid = threadIdx.x;
  const int k0 = blockIdx.y * 32, n0 = blockIdx.x * 32;
  const int c = tid & 31, rr = tid >> 5;
#pragma unroll
  for (int p = 0; p < 4; p++) {
    int r = p * 8 + rr;
    t[r][c] = W[(size_t)(k0 + r) * D + n0 + c];
  }
  __syncthreads();
#pragma unroll
  for (int p = 0; p < 4; p++) {
    int r = p * 8 + rr;                       // output row (n index)
    float v = t[c][r];                        // W[k0+c][n0+r]
    ushort_t hb = f2bf(v);
    Th[(size_t)(n0 + r) * D + k0 + c] = hb;
    Tl[(size_t)(n0 + r) * D + k0 + c] = f2bf(v - bf2f(hb));
  }
}

// ------ split-bf16 MFMA GEMM: C = (Ah+Al)@(Bh+Bl)^T' (3-term, virtual 3K) --
// A: [M][K] bf16 hi/lo row-major. Bt: [N][K] bf16 hi/lo (transposed weights).
__global__ __launch_bounds__(256) void gemm_split(const ushort_t* __restrict__ Ah,
                                                  const ushort_t* __restrict__ Al,
                                                  const ushort_t* __restrict__ Bth,
                                                  const ushort_t* __restrict__ Btl,
                                                  float* __restrict__ C,
                                                  int M, int N, int K) {
  __shared__ __align__(16) ushort_t As[2][4096];   // [128][32]
  __shared__ __align__(16) ushort_t Bs[2][4096];   // [128 cols][32 k]
  const int tid = threadIdx.x, lane = tid & 63, wid = tid >> 6;
  const int nwg = gridDim.x;
  int bid = blockIdx.x;
  int swz = (bid & 7) * (nwg >> 3) + (bid >> 3);   // XCD swizzle (nwg%8==0)
  const int nbn = N >> 7;
  const int bm = swz / nbn, bn = swz % nbn;
  const int row0 = bm << 7, col0 = bn << 7;
  const int lm = lane & 15, lg = lane >> 4;
  const int wrow = (wid >> 1) * 64, wcol = (wid & 1) * 64;
  const int KSEG = K >> 5;
  const int NT = KSEG * 3;

  f4_t acc[4][4];
#pragma unroll
  for (int m = 0; m < 4; m++)
#pragma unroll
    for (int n = 0; n < 4; n++) acc[m][n] = (f4_t){0.f, 0.f, 0.f, 0.f};

  auto stage = [&](int buf, int t) {
    int seg = t / KSEG;
    int k0 = (t % KSEG) << 5;
    const ushort_t* Ag = (seg == 2) ? Al : Ah;
    const ushort_t* Bg = (seg == 1) ? Btl : Bth;
#pragma unroll
    for (int p = 0; p < 2; p++) {
      int c = p * 256 + wid * 64 + lane;          // chunk 0..511 (16B each)
      const ushort_t* ga = Ag + (size_t)(row0 + (c >> 2)) * K + k0 + (c & 3) * 8;
      char* la = (char*)&As[buf][0] + p * 4096 + wid * 1024;
      GLOAD16(ga, la);
      const ushort_t* gb = Bg + (size_t)(col0 + (c >> 2)) * K + k0 + (c & 3) * 8;
      char* lb = (char*)&Bs[buf][0] + p * 4096 + wid * 1024;
      GLOAD16(gb, lb);
    }
  };

  stage(0, 0);
  __syncthreads();
  for (int t = 0; t < NT; t++) {
    int cur = t & 1;
    if (t + 1 < NT) stage(cur ^ 1, t + 1);
    s8_t af[4], bfr[4];
#pragma unroll
    for (int m = 0; m < 4; m++)
      af[m] = *(const s8_t*)&As[cur][(wrow + m * 16 + lm) * 32 + lg * 8];
#pragma unroll
    for (int n = 0; n < 4; n++)
      bfr[n] = *(const s8_t*)&Bs[cur][(wcol + n * 16 + lm) * 32 + lg * 8];
#pragma unroll
    for (int m = 0; m < 4; m++)
#pragma unroll
      for (int n = 0; n < 4; n++)
        acc[m][n] = MFMA16(af[m], bfr[n], acc[m][n]);
    __syncthreads();
  }
#pragma unroll
  for (int m = 0; m < 4; m++)
#pragma unroll
    for (int n = 0; n < 4; n++)
#pragma unroll
      for (int r = 0; r < 4; r++)
        C[(size_t)(row0 + wrow + m * 16 + lg * 4 + r) * N + col0 + wcol + n * 16 + lm] = acc[m][n][r];
}

// ---------------- activations: softmax/clip q,k ; gate g ; kb, vb ----------
__device__ __forceinline__ float gate_fn(float z) {
  float t = -z;
  float sp = (t > 20.f) ? t : log1pf(expf(t));   // softplus(-z)
  float g = -sp * (1.f / 16.f);                  // log_sigmoid(z)/16
  return fminf(fmaxf(g, -16.f), 16.f);
}

__global__ __launch_bounds__(256) void act_kernel(const float* __restrict__ qr,
                                                  const float* __restrict__ kr,
                                                  const float* __restrict__ vr,
                                                  float* __restrict__ qs,
                                                  float* __restrict__ ksm,
                                                  float* __restrict__ kb,
                                                  float* __restrict__ vb) {
  int wave = blockIdx.x * 4 + (threadIdx.x >> 6);  // (row*16 + h)
  int lane = threadIdx.x & 63;
  size_t base = (size_t)wave * 128;
  float q0 = qr[base + lane], q1 = qr[base + 64 + lane];
  float k0 = kr[base + lane], k1 = kr[base + 64 + lane];
  float v0 = vr[base + lane], v1 = vr[base + 64 + lane];

  float m = fmaxf(q0, q1);
  for (int o = 1; o < 64; o <<= 1) m = fmaxf(m, __shfl_xor(m, o));
  float e0 = expf(q0 - m), e1 = expf(q1 - m);
  float s = e0 + e1;
  for (int o = 1; o < 64; o <<= 1) s += __shfl_xor(s, o);
  float inv = 1.f / s;
  float qs0 = fminf(fmaxf(e0 * inv, EPSC), 1.f - EPSC) * RSQDH;
  float qs1 = fminf(fmaxf(e1 * inv, EPSC), 1.f - EPSC) * RSQDH;

  float mk = fmaxf(k0, k1);
  for (int o = 1; o < 64; o <<= 1) mk = fmaxf(mk, __shfl_xor(mk, o));
  float f0 = expf(k0 - mk), f1 = expf(k1 - mk);
  float sk = f0 + f1;
  for (int o = 1; o < 64; o <<= 1) sk += __shfl_xor(sk, o);
  float invk = 1.f / sk;
  float ks0 = fminf(fmaxf(f0 * invk, EPSC), 1.f - EPSC);
  float ks1 = fminf(fmaxf(f1 * invk, EPSC), 1.f - EPSC);

  float g0 = gate_fn(k0), g1 = gate_fn(k1);

  qs[base + lane] = qs0;        qs[base + 64 + lane] = qs1;
  ksm[base + lane] = ks0;       ksm[base + 64 + lane] = ks1;
  kb[base + lane] = ks0 * g0;   kb[base + 64 + lane] = ks1 * g1;
  vb[base + lane] = v0 * g0;    vb[base + 64 + lane] = v1 * g1;
}

// ------- per-chunk: L, attn_pre, forward substitution -> u, w --------------
__global__ __launch_bounds__(256) void chunk_uw_kernel(const float* __restrict__ qs,
                                                       const float* __restrict__ ksm,
                                                       const float* __restrict__ kb,
                                                       const float* __restrict__ vb,
                                                       float* __restrict__ u,
                                                       float* __restrict__ w,
                                                       float* __restrict__ attn) {
  __shared__ float smem[16384];          // 64KB
  float* k_s = smem;                     // [64][128]
  float* kb_s = smem + 8192;             // [64][128]
  const int tid = threadIdx.x;
  const int bh = blockIdx.x >> 4, ci = blockIdx.x & 15;
  const int rowbase = (bh >> 4) * 1024 + ci * 64;
  const int colbase = (bh & 15) * 128;

  for (int i = 0; i < 32; i++) {
    int idx = tid + i * 256;
    int r = idx >> 7, c = idx & 127;
    size_t g = (size_t)(rowbase + r) * D + colbase + c;
    k_s[idx] = ksm[g];
    kb_s[idx] = kb[g];
  }
  __syncthreads();

  float Lreg[16];
  for (int sIt = 0; sIt < 16; sIt++) {
    int e = tid + sIt * 256;             // 0..4095
    int i = e >> 6, j = e & 63;
    float accL = 0.f, accA = 0.f;
    const float* qrow = qs + (size_t)(rowbase + i) * D + colbase;
    for (int cc = 0; cc < 128; cc++) {
      int c = (cc + tid) & 127;
      float kj = k_s[j * 128 + c];
      accL += kb_s[i * 128 + c] * kj;
      accA += qrow[c] * kj;
    }
    Lreg[sIt] = (j < i) ? accL : 0.f;
    attn[(size_t)blockIdx.x * 4096 + e] = (j <= i) ? accA : 0.f;
  }
  __syncthreads();
  float* L_s = smem;
  for (int sIt = 0; sIt < 16; sIt++) L_s[tid + sIt * 256] = Lreg[sIt];
  __syncthreads();

  float x[64];
  const int c = tid & 127;
  const bool isU = (tid < 128);
  if (isU) {
#pragma unroll
    for (int j = 0; j < 64; j++) x[j] = vb[(size_t)(rowbase + j) * D + colbase + c];
  } else {
#pragma unroll
    for (int j = 0; j < 64; j++) x[j] = kb_s[j * 128 + c];
  }
#pragma unroll
  for (int i = 0; i < 64; i++) {
    float xi = x[i];
#pragma unroll
    for (int r = i + 1; r < 64; r++) x[r] -= L_s[r * 64 + i] * xi;
  }
  float* dst = isU ? u : w;
#pragma unroll
  for (int j = 0; j < 64; j++) dst[(size_t)(rowbase + j) * D + colbase + c] = x[j];
}

// ---------------- sequential scan over chunks (per b,h and dv-quarter) ----
__global__ __launch_bounds__(256) void scan_kernel(const float* __restrict__ qs,
                                                   const float* __restrict__ ksm,
                                                   const float* __restrict__ u,
                                                   const float* __restrict__ w,
                                                   const float* __restrict__ attn,
                                                   float* __restrict__ o_lin) {
  __shared__ float S_s[128 * 32];
  __shared__ float u_s[64 * 32];
  __shared__ float st[64 * 128];
  const int tid = threadIdx.x;
  const int bh = blockIdx.x;
  const int b = bh >> 4, h = bh & 15;
  const int g = blockIdx.y;
  const int colbase = h * 128;
  const int vcol = h * 128 + g * 32;
  for (int i = tid; i < 4096; i += 256) S_s[i] = 0.f;
  const int cc = tid & 31;
  const int ig = tid >> 5;
  const int i0 = ig * 8;
  const int k0 = ig * 16;

  for (int chunk = 0; chunk < 16; chunk++) {
    const int rowbase = b * 1024 + chunk * 64;
    const size_t gbase = (size_t)rowbase * D;
    __syncthreads();
    for (int idx = tid; idx < 8192; idx += 256)
      st[idx] = w[gbase + (size_t)(idx >> 7) * D + colbase + (idx & 127)];
    __syncthreads();
    {
      float acc[8] = {};
      for (int k = 0; k < 128; k++) {
        float sv = S_s[k * 32 + cc];
#pragma unroll
        for (int r = 0; r < 8; r++) acc[r] += st[(i0 + r) * 128 + k] * sv;
      }
#pragma unroll
      for (int r = 0; r < 8; r++) {
        float up = u[gbase + (size_t)(i0 + r) * D + vcol + cc] - acc[r];
        u_s[(i0 + r) * 32 + cc] = up;
      }
    }
    __syncthreads();
    for (int idx = tid; idx < 8192; idx += 256)
      st[idx] = qs[gbase + (size_t)(idx >> 7) * D + colbase + (idx & 127)];
    __syncthreads();
    {
      float acc[8] = {};
      for (int k = 0; k < 128; k++) {
        float sv = S_s[k * 32 + cc];
#pragma unroll
        for (int r = 0; r < 8; r++) acc[r] += st[(i0 + r) * 128 + k] * sv;
      }
      const float* ab = attn + (size_t)(bh * 16 + chunk) * 4096;
      for (int j = 0; j < 64; j++) {
        float uv = u_s[j * 32 + cc];
#pragma unroll
        for (int r = 0; r < 8; r++) acc[r] += ab[(i0 + r) * 64 + j] * uv;
      }
#pragma unroll
      for (int r = 0; r < 8; r++)
        o_lin[gbase + (size_t)(i0 + r) * D + vcol + cc] = acc[r];
    }
    __syncthreads();
    for (int idx = tid; idx < 8192; idx += 256)
      st[idx] = ksm[gbase + (size_t)(idx >> 7) * D + colbase + (idx & 127)];
    __syncthreads();
    {
      float acc[16] = {};
      for (int i = 0; i < 64; i++) {
        float uv = u_s[i * 32 + cc];
#pragma unroll
        for (int kk = 0; kk < 16; kk++) acc[kk] += st[i * 128 + k0 + kk] * uv;
      }
#pragma unroll
      for (int kk = 0; kk < 16; kk++) S_s[(k0 + kk) * 32 + cc] += acc[kk];
    }
  }
}

// -------- q,k -> bf16 (q pre-scaled by 1/sqrt(DH)) ------------------------
__global__ __launch_bounds__(256) void qk_to_bf16(const float* __restrict__ qr,
                                                  const float* __restrict__ kr,
                                                  ushort_t* __restrict__ qb,
                                                  ushort_t* __restrict__ kbf) {
  int i = (blockIdx.x * 256 + threadIdx.x) * 4;
  float4 q = *(const float4*)(qr + i);
  float4 k = *(const float4*)(kr + i);
  us4_t qo, ko;
  float qq[4] = {q.x, q.y, q.z, q.w}, kk2[4] = {k.x, k.y, k.z, k.w};
#pragma unroll
  for (int j = 0; j < 4; j++) {
    qo[j] = f2bf(qq[j] * RSQDH);
    ko[j] = f2bf(kk2[j]);
  }
  *(us4_t*)(qb + i) = qo;
  *(us4_t*)(kbf + i) = ko;
}

// -------- v -> transposed bf16 vt[b][h][d][n] -----------------------------
__global__ __launch_bounds__(256) void v_transpose(const float* __restrict__ vr,
                                                   ushort_t* __restrict__ vt) {
  __shared__ float t[32][33];
  const int tid = threadIdx.x;
  const int n0 = blockIdx.x * 32;      // 32 tiles
  const int d0 = blockIdx.y * 32;      // 4 tiles
  const int bh = blockIdx.z;           // 32
  const int b = bh >> 4, h = bh & 15;
  const int c = tid & 31, rr = tid >> 5;
#pragma unroll
  for (int p = 0; p < 4; p++) {
    int r = p * 8 + rr;
    t[r][c] = vr[(size_t)(b * 1024 + n0 + r) * D + h * 128 + d0 + c];
  }
  __syncthreads();
#pragma unroll
  for (int p = 0; p < 4; p++) {
    int r = p * 8 + rr;                // d offset
    vt[(size_t)(bh * 128 + d0 + r) * 1024 + n0 + c] = f2bf(t[c][r]);
  }
}

// -------- MFMA bf16 flash attention + 0.5/0.5 mix + bf16-split out --------
__global__ __launch_bounds__(256) void attn_mfma(const ushort_t* __restrict__ qb,
                                                 const ushort_t* __restrict__ kb,
                                                 const ushort_t* __restrict__ vt,
                                                 const float* __restrict__ o_lin,
                                                 ushort_t* __restrict__ mixh,
                                                 ushort_t* __restrict__ mixl) {
  __shared__ __align__(16) ushort_t K_s[8192];    // [64 keys][128 d] swizzled
  __shared__ __align__(16) ushort_t V_s[8192];    // [128 d][64 keys] swizzled
  __shared__ __align__(16) ushort_t P_s[4][1152]; // per-wave [16][72]
  const int tid = threadIdx.x;
  const int lane = tid & 63, wid = tid >> 6;
  const int bh = blockIdx.x;
  const int b = bh >> 4, h = bh & 15;
  const int qt = blockIdx.y;
  const int lm = lane & 15, lg = lane >> 4;

  s8_t qf[4];
  const size_t qrowG = (size_t)(b * 1024 + qt * 64 + wid * 16 + lm);
#pragma unroll
  for (int kb4 = 0; kb4 < 4; kb4++)
    qf[kb4] = *(const s8_t*)(qb + qrowG * D + h * 128 + kb4 * 32 + lg * 8);

  f4_t o[8];
#pragma unroll
  for (int n = 0; n < 8; n++) o[n] = (f4_t){0.f, 0.f, 0.f, 0.f};
  float mrow[4] = {-INFINITY, -INFINITY, -INFINITY, -INFINITY};
  float lrow[4] = {0.f, 0.f, 0.f, 0.f};
  const int myq = qt * 64 + wid * 16 + lg * 4;   // + r

  for (int kt = 0; kt <= qt; kt++) {
    __syncthreads();
    // stage K [64][128]
#pragma unroll
    for (int p = 0; p < 4; p++) {
      int c = tid + p * 256;
      int key = c >> 4, dc = c & 15;
      s8_t v = *(const s8_t*)(kb + (size_t)(b * 1024 + kt * 64 + key) * D + h * 128 + dc * 8);
      int byo = key * 256 + ((dc * 16) ^ ((key & 7) << 4));
      *(s8_t*)((char*)K_s + byo) = v;
    }
    // stage Vt [128][64]
#pragma unroll
    for (int p = 0; p < 4; p++) {
      int c = tid + p * 256;
      int d = c >> 3, nc = c & 7;
      s8_t v = *(const s8_t*)(vt + (size_t)(bh * 128 + d) * 1024 + kt * 64 + nc * 8);
      int byo = d * 128 + ((nc * 16) ^ ((d & 7) << 4));
      *(s8_t*)((char*)V_s + byo) = v;
    }
    __syncthreads();

    // scores S[q16][key64]
    f4_t s[4];
#pragma unroll
    for (int ks = 0; ks < 4; ks++) {
      f4_t a = (f4_t){0.f, 0.f, 0.f, 0.f};
      int key = ks * 16 + lm;
#pragma unroll
      for (int kb4 = 0; kb4 < 4; kb4++) {
        int byo = key * 256 + ((kb4 * 64 + lg * 16) ^ ((key & 7) << 4));
        s8_t kf = *(const s8_t*)((char*)K_s + byo);
        a = MFMA16(qf[kb4], kf, a);
      }
      s[ks] = a;
    }
    if (kt == qt) {
#pragma unroll
      for (int ks = 0; ks < 4; ks++) {
        int key = kt * 64 + ks * 16 + lm;
#pragma unroll
        for (int r = 0; r < 4; r++)
          if (key > myq + r) s[ks][r] = -INFINITY;
      }
    }
    float mloc[4];
#pragma unroll
    for (int r = 0; r < 4; r++) {
      mloc[r] = fmaxf(fmaxf(s[0][r], s[1][r]), fmaxf(s[2][r], s[3][r]));
      mloc[r] = fmaxf(mloc[r], __shfl_xor(mloc[r], 1));
      mloc[r] = fmaxf(mloc[r], __shfl_xor(mloc[r], 2));
      mloc[r] = fmaxf(mloc[r], __shfl_xor(mloc[r], 4));
      mloc[r] = fmaxf(mloc[r], __shfl_xor(mloc[r], 8));
    }
    float scale[4];
#pragma unroll
    for (int r = 0; r < 4; r++) {
      float mn = fmaxf(mrow[r], mloc[r]);
      scale[r] = __expf(mrow[r] - mn);
      mrow[r] = mn;
    }
    float lad[4] = {0.f, 0.f, 0.f, 0.f};
#pragma unroll
    for (int ks = 0; ks < 4; ks++)
#pragma unroll
      for (int r = 0; r < 4; r++) {
        float p = __expf(s[ks][r] - mrow[r]);
        lad[r] += p;
        P_s[wid][(lg * 4 + r) * 72 + ks * 16 + lm] = f2bf(p);
      }
#pragma unroll
    for (int r = 0; r < 4; r++) {
      lad[r] += __shfl_xor(lad[r], 1);
      lad[r] += __shfl_xor(lad[r], 2);
      lad[r] += __shfl_xor(lad[r], 4);
      lad[r] += __shfl_xor(lad[r], 8);
      lrow[r] = lrow[r] * scale[r] + lad[r];
    }
#pragma unroll
    for (int n = 0; n < 8; n++)
#pragma unroll
      for (int r = 0; r < 4; r++) o[n][r] *= scale[r];

    // PV
    s8_t pf[2];
#pragma unroll
    for (int ksl = 0; ksl < 2; ksl++)
      pf[ksl] = *(const s8_t*)&P_s[wid][lm * 72 + ksl * 32 + lg * 8];
#pragma unroll
    for (int n = 0; n < 8; n++) {
      int d = n * 16 + lm;
#pragma unroll
      for (int ksl = 0; ksl < 2; ksl++) {
        int byo = d * 128 + ((ksl * 64 + lg * 16) ^ ((d & 7) << 4));
        s8_t vf = *(const s8_t*)((char*)V_s + byo);
        o[n] = MFMA16(pf[ksl], vf, o[n]);
      }
    }
  }

  float invl[4];
#pragma unroll
  for (int r = 0; r < 4; r++) invl[r] = 1.f / lrow[r];
#pragma unroll
  for (int n = 0; n < 8; n++)
#pragma unroll
    for (int r = 0; r < 4; r++) {
      size_t G = (size_t)(b * 1024 + qt * 64 + wid * 16 + lg * 4 + r);
      int dcol = h * 128 + n * 16 + lm;
      float mix = 0.5f * (o[n][r] * invl[r]) + 0.5f * o_lin[G * D + dcol];
      ushort_t hb = f2bf(mix);
      mixh[G * D + dcol] = hb;
      mixl[G * D + dcol] = f2bf(mix - bf2f(hb));
    }
}

// ---------------------------------------------------------------------------
extern "C" void kernel_launch(void* const* d_in, const int* in_sizes, int n_in,
                              void* d_out, int out_size, void* d_ws, size_t ws_size,
                              hipStream_t stream) {
  const float* x  = (const float*)d_in[0];
  const float* Wq = (const float*)d_in[1];
  const float* Wk = (const float*)d_in[2];
  const float* Wv = (const float*)d_in[3];
  const float* Wo = (const float*)d_in[4];
  float* out = (float*)d_out;
  float* ws = (float*)d_ws;

  const size_t B = (size_t)NROWS * D;   // 4,194,304 floats per slot
  float* q_raw = ws + 0 * B;            // S0 -> later mix_hi/mix_lo? (hi only)
  float* k_raw = ws + 1 * B;            // S1 -> later mix_lo
  float* v_raw = ws + 2 * B;            // S2
  float* q_s   = ws + 3 * B;            // S3 -> later qb16
  float* k_sm  = ws + 4 * B;            // S4 -> later kb16
  float* kbuf  = ws + 5 * B;            // S5 -> o_lin
  float* vbuf  = ws + 6 * B;            // S6 -> vt16
  float* u     = ws + 7 * B;            // S7 (x_hi first)
  float* w     = ws + 8 * B;            // S8 (x_lo first)
  float* attn  = ws + 9 * B;            // S9 (uses half)
  float* wt    = ws + 10 * B;           // S10: Wt_hi + Wt_lo (bf16)
  float* o_lin = kbuf;

  ushort_t* x_hi = (ushort_t*)u;
  ushort_t* x_lo = (ushort_t*)w;
  ushort_t* Wt_h = (ushort_t*)wt;
  ushort_t* Wt_l = Wt_h + B;
  ushort_t* qb16 = (ushort_t*)q_s;
  ushort_t* kb16 = (ushort_t*)k_sm;
  ushort_t* vt16 = (ushort_t*)vbuf;
  ushort_t* mixh = (ushort_t*)q_raw;
  ushort_t* mixl = (ushort_t*)k_raw;

  dim3 wg(64, 64);

  split_f32<<<4096, 256, 0, stream>>>(x, x_hi, x_lo);
  wsplit_t<<<wg, 256, 0, stream>>>(Wq, Wt_h, Wt_l);
  gemm_split<<<256, 256, 0, stream>>>(x_hi, x_lo, Wt_h, Wt_l, q_raw, NROWS, D, D);
  wsplit_t<<<wg, 256, 0, stream>>>(Wk, Wt_h, Wt_l);
  gemm_split<<<256, 256, 0, stream>>>(x_hi, x_lo, Wt_h, Wt_l, k_raw, NROWS, D, D);
  wsplit_t<<<wg, 256, 0, stream>>>(Wv, Wt_h, Wt_l);
  gemm_split<<<256, 256, 0, stream>>>(x_hi, x_lo, Wt_h, Wt_l, v_raw, NROWS, D, D);

  act_kernel<<<8192, 256, 0, stream>>>(q_raw, k_raw, v_raw, q_s, k_sm, kbuf, vbuf);
  chunk_uw_kernel<<<512, 256, 0, stream>>>(q_s, k_sm, kbuf, vbuf, u, w, attn);
  scan_kernel<<<dim3(32, 4), 256, 0, stream>>>(q_s, k_sm, u, w, attn, o_lin);

  qk_to_bf16<<<4096, 256, 0, stream>>>(q_raw, k_raw, qb16, kb16);
  v_transpose<<<dim3(32, 4, 32), 256, 0, stream>>>(v_raw, vt16);
  attn_mfma<<<dim3(32, 16), 256, 0, stream>>>(qb16, kb16, vt16, o_lin, mixh, mixl);

  wsplit_t<<<wg, 256, 0, stream>>>(Wo, Wt_h, Wt_l);
  gemm_split<<<256, 256, 0, stream>>>(mixh, mixl, Wt_h, Wt_l, out, NROWS, D, D);
}

// Round 4
// 850.079 us; speedup vs baseline: 2.7408x; 1.2180x over previous
//
#include <hip/hip_runtime.h>
#include <hip/hip_bf16.h>
#include <math.h>

#define D 2048
#define NROWS 2048      // b*n
#define H 16
#define DH 128
#define CHK 64
#define NC 16
#define EPSC 1e-6f
#define RSQDH 0.08838834764831845f   // 128^-0.5

typedef unsigned short ushort_t;
typedef __attribute__((ext_vector_type(4))) float f4_t;
typedef __attribute__((ext_vector_type(8))) short s8_t;
typedef __attribute__((ext_vector_type(4))) unsigned short us4_t;

#define MFMA16(a, b, c) __builtin_amdgcn_mfma_f32_16x16x32_bf16((a), (b), (c), 0, 0, 0)
#define GLOAD16(g, l) __builtin_amdgcn_global_load_lds((const __attribute__((address_space(1))) unsigned int*)(g), (__attribute__((address_space(3))) unsigned int*)(l), 16, 0, 0)

__device__ __forceinline__ ushort_t f2bf(float f) {
  union { float f; unsigned u; } v; v.f = f;
  unsigned r = (v.u + 0x7fffu + ((v.u >> 16) & 1u)) >> 16;
  return (ushort_t)r;
}
__device__ __forceinline__ float bf2f(ushort_t h) {
  union { unsigned u; float f; } v; v.u = ((unsigned)h) << 16;
  return v.f;
}

// ---------------- split fp32 -> bf16 hi/lo (elementwise) -------------------
__global__ __launch_bounds__(256) void split_f32(const float* __restrict__ in,
                                                 ushort_t* __restrict__ hi,
                                                 ushort_t* __restrict__ lo) {
  int i = (blockIdx.x * 256 + threadIdx.x) * 4;
  float4 v = *(const float4*)(in + i);
  us4_t h, l;
  float vv[4] = {v.x, v.y, v.z, v.w};
#pragma unroll
  for (int j = 0; j < 4; j++) {
    ushort_t hb = f2bf(vv[j]);
    h[j] = hb;
    l[j] = f2bf(vv[j] - bf2f(hb));
  }
  *(us4_t*)(hi + i) = h;
  *(us4_t*)(lo + i) = l;
}

// ------------- weight: transpose + split -> Wt_hi[n][k], Wt_lo[n][k] -------
__global__ __launch_bounds__(256) void wsplit_t(const float* __restrict__ W,
                                                ushort_t* __restrict__ Th,
                                                ushort_t* __restrict__ Tl) {
  __shared__ float t[32][33];
  const int tid = threadIdx.x;
  const int k0 = blockIdx.y * 32, n0 = blockIdx.x * 32;
  const int c = tid & 31, rr = tid >> 5;
#pragma unroll
  for (int p = 0; p < 4; p++) {
    int r = p * 8 + rr;
    t[r][c] = W[(size_t)(k0 + r) * D + n0 + c];
  }
  __syncthreads();
#pragma unroll
  for (int p = 0; p < 4; p++) {
    int r = p * 8 + rr;                       // output row (n index)
    float v = t[c][r];                        // W[k0+c][n0+r]
    ushort_t hb = f2bf(v);
    Th[(size_t)(n0 + r) * D + k0 + c] = hb;
    Tl[(size_t)(n0 + r) * D + k0 + c] = f2bf(v - bf2f(hb));
  }
}

// ------ split-bf16 MFMA GEMM: C = (Ah+Al)@(Bh+Bl)^T' (3-term, virtual 3K) --
__global__ __launch_bounds__(256) void gemm_split(const ushort_t* __restrict__ Ah,
                                                  const ushort_t* __restrict__ Al,
                                                  const ushort_t* __restrict__ Bth,
                                                  const ushort_t* __restrict__ Btl,
                                                  float* __restrict__ C,
                                                  int M, int N, int K) {
  __shared__ __align__(16) ushort_t As[2][4096];   // [128][32]
  __shared__ __align__(16) ushort_t Bs[2][4096];   // [128 cols][32 k]
  const int tid = threadIdx.x, lane = tid & 63, wid = tid >> 6;
  const int nwg = gridDim.x;
  int bid = blockIdx.x;
  int swz = (bid & 7) * (nwg >> 3) + (bid >> 3);   // XCD swizzle (nwg%8==0)
  const int nbn = N >> 7;
  const int bm = swz / nbn, bn = swz % nbn;
  const int row0 = bm << 7, col0 = bn << 7;
  const int lm = lane & 15, lg = lane >> 4;
  const int wrow = (wid >> 1) * 64, wcol = (wid & 1) * 64;
  const int KSEG = K >> 5;
  const int NT = KSEG * 3;

  f4_t acc[4][4];
#pragma unroll
  for (int m = 0; m < 4; m++)
#pragma unroll
    for (int n = 0; n < 4; n++) acc[m][n] = (f4_t){0.f, 0.f, 0.f, 0.f};

  auto stage = [&](int buf, int t) {
    int seg = t / KSEG;
    int k0 = (t % KSEG) << 5;
    const ushort_t* Ag = (seg == 2) ? Al : Ah;
    const ushort_t* Bg = (seg == 1) ? Btl : Bth;
#pragma unroll
    for (int p = 0; p < 2; p++) {
      int c = p * 256 + wid * 64 + lane;          // chunk 0..511 (16B each)
      const ushort_t* ga = Ag + (size_t)(row0 + (c >> 2)) * K + k0 + (c & 3) * 8;
      char* la = (char*)&As[buf][0] + p * 4096 + wid * 1024;
      GLOAD16(ga, la);
      const ushort_t* gb = Bg + (size_t)(col0 + (c >> 2)) * K + k0 + (c & 3) * 8;
      char* lb = (char*)&Bs[buf][0] + p * 4096 + wid * 1024;
      GLOAD16(gb, lb);
    }
  };

  stage(0, 0);
  __syncthreads();
  for (int t = 0; t < NT; t++) {
    int cur = t & 1;
    if (t + 1 < NT) stage(cur ^ 1, t + 1);
    s8_t af[4], bfr[4];
#pragma unroll
    for (int m = 0; m < 4; m++)
      af[m] = *(const s8_t*)&As[cur][(wrow + m * 16 + lm) * 32 + lg * 8];
#pragma unroll
    for (int n = 0; n < 4; n++)
      bfr[n] = *(const s8_t*)&Bs[cur][(wcol + n * 16 + lm) * 32 + lg * 8];
#pragma unroll
    for (int m = 0; m < 4; m++)
#pragma unroll
      for (int n = 0; n < 4; n++)
        acc[m][n] = MFMA16(af[m], bfr[n], acc[m][n]);
    __syncthreads();
  }
#pragma unroll
  for (int m = 0; m < 4; m++)
#pragma unroll
    for (int n = 0; n < 4; n++)
#pragma unroll
      for (int r = 0; r < 4; r++)
        C[(size_t)(row0 + wrow + m * 16 + lg * 4 + r) * N + col0 + wcol + n * 16 + lm] = acc[m][n][r];
}

// ---------------- activations: softmax/clip q,k ; gate g ; kb, vb ----------
__device__ __forceinline__ float gate_fn(float z) {
  float t = -z;
  float sp = (t > 20.f) ? t : log1pf(expf(t));   // softplus(-z)
  float g = -sp * (1.f / 16.f);                  // log_sigmoid(z)/16
  return fminf(fmaxf(g, -16.f), 16.f);
}

__global__ __launch_bounds__(256) void act_kernel(const float* __restrict__ qr,
                                                  const float* __restrict__ kr,
                                                  const float* __restrict__ vr,
                                                  float* __restrict__ qs,
                                                  float* __restrict__ ksm,
                                                  float* __restrict__ kb,
                                                  float* __restrict__ vb) {
  int wave = blockIdx.x * 4 + (threadIdx.x >> 6);  // (row*16 + h)
  int lane = threadIdx.x & 63;
  size_t base = (size_t)wave * 128;
  float q0 = qr[base + lane], q1 = qr[base + 64 + lane];
  float k0 = kr[base + lane], k1 = kr[base + 64 + lane];
  float v0 = vr[base + lane], v1 = vr[base + 64 + lane];

  float m = fmaxf(q0, q1);
  for (int o = 1; o < 64; o <<= 1) m = fmaxf(m, __shfl_xor(m, o));
  float e0 = expf(q0 - m), e1 = expf(q1 - m);
  float s = e0 + e1;
  for (int o = 1; o < 64; o <<= 1) s += __shfl_xor(s, o);
  float inv = 1.f / s;
  float qs0 = fminf(fmaxf(e0 * inv, EPSC), 1.f - EPSC) * RSQDH;
  float qs1 = fminf(fmaxf(e1 * inv, EPSC), 1.f - EPSC) * RSQDH;

  float mk = fmaxf(k0, k1);
  for (int o = 1; o < 64; o <<= 1) mk = fmaxf(mk, __shfl_xor(mk, o));
  float f0 = expf(k0 - mk), f1 = expf(k1 - mk);
  float sk = f0 + f1;
  for (int o = 1; o < 64; o <<= 1) sk += __shfl_xor(sk, o);
  float invk = 1.f / sk;
  float ks0 = fminf(fmaxf(f0 * invk, EPSC), 1.f - EPSC);
  float ks1 = fminf(fmaxf(f1 * invk, EPSC), 1.f - EPSC);

  float g0 = gate_fn(k0), g1 = gate_fn(k1);

  qs[base + lane] = qs0;        qs[base + 64 + lane] = qs1;
  ksm[base + lane] = ks0;       ksm[base + 64 + lane] = ks1;
  kb[base + lane] = ks0 * g0;   kb[base + 64 + lane] = ks1 * g1;
  vb[base + lane] = v0 * g0;    vb[base + 64 + lane] = v1 * g1;
}

// ------- per-chunk: L, attn_pre, forward substitution -> u, w --------------
__global__ __launch_bounds__(256) void chunk_uw_kernel(const float* __restrict__ qs,
                                                       const float* __restrict__ ksm,
                                                       const float* __restrict__ kb,
                                                       const float* __restrict__ vb,
                                                       float* __restrict__ u,
                                                       float* __restrict__ w,
                                                       float* __restrict__ attn) {
  __shared__ float smem[16384];          // 64KB
  float* k_s = smem;                     // [64][128]
  float* kb_s = smem + 8192;             // [64][128]
  const int tid = threadIdx.x;
  const int bh = blockIdx.x >> 4, ci = blockIdx.x & 15;
  const int rowbase = (bh >> 4) * 1024 + ci * 64;
  const int colbase = (bh & 15) * 128;

  for (int i = 0; i < 32; i++) {
    int idx = tid + i * 256;
    int r = idx >> 7, c = idx & 127;
    size_t g = (size_t)(rowbase + r) * D + colbase + c;
    k_s[idx] = ksm[g];
    kb_s[idx] = kb[g];
  }
  __syncthreads();

  float Lreg[16];
  for (int sIt = 0; sIt < 16; sIt++) {
    int e = tid + sIt * 256;             // 0..4095
    int i = e >> 6, j = e & 63;
    float accL = 0.f, accA = 0.f;
    const float* qrow = qs + (size_t)(rowbase + i) * D + colbase;
    for (int cc = 0; cc < 128; cc++) {
      int c = (cc + tid) & 127;
      float kj = k_s[j * 128 + c];
      accL += kb_s[i * 128 + c] * kj;
      accA += qrow[c] * kj;
    }
    Lreg[sIt] = (j < i) ? accL : 0.f;
    attn[(size_t)blockIdx.x * 4096 + e] = (j <= i) ? accA : 0.f;
  }
  __syncthreads();
  float* L_s = smem;
  for (int sIt = 0; sIt < 16; sIt++) L_s[tid + sIt * 256] = Lreg[sIt];
  __syncthreads();

  float x[64];
  const int c = tid & 127;
  const bool isU = (tid < 128);
  if (isU) {
#pragma unroll
    for (int j = 0; j < 64; j++) x[j] = vb[(size_t)(rowbase + j) * D + colbase + c];
  } else {
#pragma unroll
    for (int j = 0; j < 64; j++) x[j] = kb_s[j * 128 + c];
  }
#pragma unroll
  for (int i = 0; i < 64; i++) {
    float xi = x[i];
#pragma unroll
    for (int r = i + 1; r < 64; r++) x[r] -= L_s[r * 64 + i] * xi;
  }
  float* dst = isU ? u : w;
#pragma unroll
  for (int j = 0; j < 64; j++) dst[(size_t)(rowbase + j) * D + colbase + c] = x[j];
}

// ------- sequential scan over chunks: grid(32 bh, 8 vgroups), 512 thr ------
// Latency-optimized: single merged staging phase per chunk (w,q,k,attn,u all
// in flight together), 3 syncs/chunk, 128KB LDS, 1 WG/CU, 256 WGs.
__global__ __launch_bounds__(512) void scan_kernel(const float* __restrict__ qs,
                                                   const float* __restrict__ ksm,
                                                   const float* __restrict__ u,
                                                   const float* __restrict__ w,
                                                   const float* __restrict__ attn,
                                                   float* __restrict__ o_lin) {
  __shared__ float w_s[64 * 132];   // +4 pad: per-wave row addrs on distinct banks
  __shared__ float q_s2[64 * 132];
  __shared__ float k_s2[64 * 132];
  __shared__ float a_s[64 * 68];
  __shared__ float S_s[128 * 16];
  __shared__ float u_s[64 * 16];
  const int tid = threadIdx.x;
  const int bh = blockIdx.x;
  const int b = bh >> 4, h = bh & 15;
  const int g = blockIdx.y;            // 0..7 (16 dv cols each)
  const int colbase = h * 128;
  const int vcol = h * 128 + g * 16;
  const int c = tid & 15;
  const int i2 = tid >> 4;             // 0..31
  const int i0 = i2 * 2;               // phase1/2 row pair
  const int k0 = i2 * 4;               // phase3 rows

  for (int i = tid; i < 2048; i += 512) S_s[i] = 0.f;

  for (int chunk = 0; chunk < 16; chunk++) {
    const int rowbase = b * 1024 + chunk * 64;
    const size_t gbase = (size_t)rowbase * D;
    // ---- merged staging: w,q,k [64][128] fp32 + attn [64][64] + u regs ----
#pragma unroll
    for (int it = 0; it < 4; it++) {
      int f4 = tid + it * 512;           // 0..2047
      int r = f4 >> 5, c4 = (f4 & 31) * 4;
      float4 wv = *(const float4*)(w + gbase + (size_t)r * D + colbase + c4);
      *(float4*)&w_s[r * 132 + c4] = wv;
      float4 qv = *(const float4*)(qs + gbase + (size_t)r * D + colbase + c4);
      *(float4*)&q_s2[r * 132 + c4] = qv;
      float4 kv = *(const float4*)(ksm + gbase + (size_t)r * D + colbase + c4);
      *(float4*)&k_s2[r * 132 + c4] = kv;
    }
    const float* ab = attn + (size_t)(bh * 16 + chunk) * 4096;
#pragma unroll
    for (int it = 0; it < 2; it++) {
      int f4 = tid + it * 512;           // 0..1023
      int r = f4 >> 4, c4 = (f4 & 15) * 4;
      float4 av = *(const float4*)(ab + r * 64 + c4);
      *(float4*)&a_s[r * 68 + c4] = av;
    }
    float u0 = u[gbase + (size_t)i0 * D + vcol + c];
    float u1 = u[gbase + (size_t)(i0 + 1) * D + vcol + c];
    __syncthreads();                     // A: staging + S_s update visible
    // ---- phase1: u' = u - w @ S ----
    float a0 = 0.f, a1 = 0.f;
    for (int k = 0; k < 128; k++) {
      float sv = S_s[k * 16 + c];
      a0 += w_s[i0 * 132 + k] * sv;
      a1 += w_s[(i0 + 1) * 132 + k] * sv;
    }
    u_s[i0 * 16 + c] = u0 - a0;
    u_s[(i0 + 1) * 16 + c] = u1 - a1;
    __syncthreads();                     // B: u' visible
    // ---- phase2: o = q@S + attn@u' (global write) + phase3-acc in regs ----
    float o0 = 0.f, o1 = 0.f;
    for (int k = 0; k < 128; k++) {
      float sv = S_s[k * 16 + c];
      o0 += q_s2[i0 * 132 + k] * sv;
      o1 += q_s2[(i0 + 1) * 132 + k] * sv;
    }
    for (int j = 0; j < 64; j++) {
      float uv = u_s[j * 16 + c];
      o0 += a_s[i0 * 68 + j] * uv;
      o1 += a_s[(i0 + 1) * 68 + j] * uv;
    }
    o_lin[gbase + (size_t)i0 * D + vcol + c] = o0;
    o_lin[gbase + (size_t)(i0 + 1) * D + vcol + c] = o1;
    float s3[4] = {0.f, 0.f, 0.f, 0.f};
    for (int i = 0; i < 64; i++) {
      float uv = u_s[i * 16 + c];
#pragma unroll
      for (int r = 0; r < 4; r++) s3[r] += k_s2[i * 132 + k0 + r] * uv;
    }
    __syncthreads();                     // C: all shared reads done
    // ---- S update (raced only against next staging, disjoint regions) ----
#pragma unroll
    for (int r = 0; r < 4; r++) S_s[(k0 + r) * 16 + c] += s3[r];
  }
}

// -------- q,k -> bf16 (q pre-scaled by 1/sqrt(DH)) ------------------------
__global__ __launch_bounds__(256) void qk_to_bf16(const float* __restrict__ qr,
                                                  const float* __restrict__ kr,
                                                  ushort_t* __restrict__ qb,
                                                  ushort_t* __restrict__ kbf) {
  int i = (blockIdx.x * 256 + threadIdx.x) * 4;
  float4 q = *(const float4*)(qr + i);
  float4 k = *(const float4*)(kr + i);
  us4_t qo, ko;
  float qq[4] = {q.x, q.y, q.z, q.w}, kk2[4] = {k.x, k.y, k.z, k.w};
#pragma unroll
  for (int j = 0; j < 4; j++) {
    qo[j] = f2bf(qq[j] * RSQDH);
    ko[j] = f2bf(kk2[j]);
  }
  *(us4_t*)(qb + i) = qo;
  *(us4_t*)(kbf + i) = ko;
}

// -------- v -> transposed bf16 vt[b][h][d][n] -----------------------------
__global__ __launch_bounds__(256) void v_transpose(const float* __restrict__ vr,
                                                   ushort_t* __restrict__ vt) {
  __shared__ float t[32][33];
  const int tid = threadIdx.x;
  const int n0 = blockIdx.x * 32;      // 32 tiles
  const int d0 = blockIdx.y * 32;      // 4 tiles
  const int bh = blockIdx.z;           // 32
  const int b = bh >> 4, h = bh & 15;
  const int c = tid & 31, rr = tid >> 5;
#pragma unroll
  for (int p = 0; p < 4; p++) {
    int r = p * 8 + rr;
    t[r][c] = vr[(size_t)(b * 1024 + n0 + r) * D + h * 128 + d0 + c];
  }
  __syncthreads();
#pragma unroll
  for (int p = 0; p < 4; p++) {
    int r = p * 8 + rr;                // d offset
    vt[(size_t)(bh * 128 + d0 + r) * 1024 + n0 + c] = f2bf(t[c][r]);
  }
}

// -------- MFMA bf16 flash attention + 0.5/0.5 mix + bf16-split out --------
__global__ __launch_bounds__(256) void attn_mfma(const ushort_t* __restrict__ qb,
                                                 const ushort_t* __restrict__ kb,
                                                 const ushort_t* __restrict__ vt,
                                                 const float* __restrict__ o_lin,
                                                 ushort_t* __restrict__ mixh,
                                                 ushort_t* __restrict__ mixl) {
  __shared__ __align__(16) ushort_t K_s[8192];    // [64 keys][128 d] swizzled
  __shared__ __align__(16) ushort_t V_s[8192];    // [128 d][64 keys] swizzled
  __shared__ __align__(16) ushort_t P_s[4][1152]; // per-wave [16][72]
  const int tid = threadIdx.x;
  const int lane = tid & 63, wid = tid >> 6;
  const int bh = blockIdx.x;
  const int b = bh >> 4, h = bh & 15;
  const int qt = blockIdx.y;
  const int lm = lane & 15, lg = lane >> 4;

  s8_t qf[4];
  const size_t qrowG = (size_t)(b * 1024 + qt * 64 + wid * 16 + lm);
#pragma unroll
  for (int kb4 = 0; kb4 < 4; kb4++)
    qf[kb4] = *(const s8_t*)(qb + qrowG * D + h * 128 + kb4 * 32 + lg * 8);

  f4_t o[8];
#pragma unroll
  for (int n = 0; n < 8; n++) o[n] = (f4_t){0.f, 0.f, 0.f, 0.f};
  float mrow[4] = {-INFINITY, -INFINITY, -INFINITY, -INFINITY};
  float lrow[4] = {0.f, 0.f, 0.f, 0.f};
  const int myq = qt * 64 + wid * 16 + lg * 4;   // + r

  for (int kt = 0; kt <= qt; kt++) {
    __syncthreads();
    // stage K [64][128]
#pragma unroll
    for (int p = 0; p < 4; p++) {
      int c = tid + p * 256;
      int key = c >> 4, dc = c & 15;
      s8_t v = *(const s8_t*)(kb + (size_t)(b * 1024 + kt * 64 + key) * D + h * 128 + dc * 8);
      int byo = key * 256 + ((dc * 16) ^ ((key & 7) << 4));
      *(s8_t*)((char*)K_s + byo) = v;
    }
    // stage Vt [128][64]
#pragma unroll
    for (int p = 0; p < 4; p++) {
      int c = tid + p * 256;
      int d = c >> 3, nc = c & 7;
      s8_t v = *(const s8_t*)(vt + (size_t)(bh * 128 + d) * 1024 + kt * 64 + nc * 8);
      int byo = d * 128 + ((nc * 16) ^ ((d & 7) << 4));
      *(s8_t*)((char*)V_s + byo) = v;
    }
    __syncthreads();

    // scores S[q16][key64]
    f4_t s[4];
#pragma unroll
    for (int ks = 0; ks < 4; ks++) {
      f4_t a = (f4_t){0.f, 0.f, 0.f, 0.f};
      int key = ks * 16 + lm;
#pragma unroll
      for (int kb4 = 0; kb4 < 4; kb4++) {
        int byo = key * 256 + ((kb4 * 64 + lg * 16) ^ ((key & 7) << 4));
        s8_t kf = *(const s8_t*)((char*)K_s + byo);
        a = MFMA16(qf[kb4], kf, a);
      }
      s[ks] = a;
    }
    if (kt == qt) {
#pragma unroll
      for (int ks = 0; ks < 4; ks++) {
        int key = kt * 64 + ks * 16 + lm;
#pragma unroll
        for (int r = 0; r < 4; r++)
          if (key > myq + r) s[ks][r] = -INFINITY;
      }
    }
    float mloc[4];
#pragma unroll
    for (int r = 0; r < 4; r++) {
      mloc[r] = fmaxf(fmaxf(s[0][r], s[1][r]), fmaxf(s[2][r], s[3][r]));
      mloc[r] = fmaxf(mloc[r], __shfl_xor(mloc[r], 1));
      mloc[r] = fmaxf(mloc[r], __shfl_xor(mloc[r], 2));
      mloc[r] = fmaxf(mloc[r], __shfl_xor(mloc[r], 4));
      mloc[r] = fmaxf(mloc[r], __shfl_xor(mloc[r], 8));
    }
    float scale[4];
#pragma unroll
    for (int r = 0; r < 4; r++) {
      float mn = fmaxf(mrow[r], mloc[r]);
      scale[r] = __expf(mrow[r] - mn);
      mrow[r] = mn;
    }
    float lad[4] = {0.f, 0.f, 0.f, 0.f};
#pragma unroll
    for (int ks = 0; ks < 4; ks++)
#pragma unroll
      for (int r = 0; r < 4; r++) {
        float p = __expf(s[ks][r] - mrow[r]);
        lad[r] += p;
        P_s[wid][(lg * 4 + r) * 72 + ks * 16 + lm] = f2bf(p);
      }
#pragma unroll
    for (int r = 0; r < 4; r++) {
      lad[r] += __shfl_xor(lad[r], 1);
      lad[r] += __shfl_xor(lad[r], 2);
      lad[r] += __shfl_xor(lad[r], 4);
      lad[r] += __shfl_xor(lad[r], 8);
      lrow[r] = lrow[r] * scale[r] + lad[r];
    }
#pragma unroll
    for (int n = 0; n < 8; n++)
#pragma unroll
      for (int r = 0; r < 4; r++) o[n][r] *= scale[r];

    // PV
    s8_t pf[2];
#pragma unroll
    for (int ksl = 0; ksl < 2; ksl++)
      pf[ksl] = *(const s8_t*)&P_s[wid][lm * 72 + ksl * 32 + lg * 8];
#pragma unroll
    for (int n = 0; n < 8; n++) {
      int d = n * 16 + lm;
#pragma unroll
      for (int ksl = 0; ksl < 2; ksl++) {
        int byo = d * 128 + ((ksl * 64 + lg * 16) ^ ((d & 7) << 4));
        s8_t vf = *(const s8_t*)((char*)V_s + byo);
        o[n] = MFMA16(pf[ksl], vf, o[n]);
      }
    }
  }

  float invl[4];
#pragma unroll
  for (int r = 0; r < 4; r++) invl[r] = 1.f / lrow[r];
#pragma unroll
  for (int n = 0; n < 8; n++)
#pragma unroll
    for (int r = 0; r < 4; r++) {
      size_t G = (size_t)(b * 1024 + qt * 64 + wid * 16 + lg * 4 + r);
      int dcol = h * 128 + n * 16 + lm;
      float mix = 0.5f * (o[n][r] * invl[r]) + 0.5f * o_lin[G * D + dcol];
      ushort_t hb = f2bf(mix);
      mixh[G * D + dcol] = hb;
      mixl[G * D + dcol] = f2bf(mix - bf2f(hb));
    }
}

// ---------------------------------------------------------------------------
extern "C" void kernel_launch(void* const* d_in, const int* in_sizes, int n_in,
                              void* d_out, int out_size, void* d_ws, size_t ws_size,
                              hipStream_t stream) {
  const float* x  = (const float*)d_in[0];
  const float* Wq = (const float*)d_in[1];
  const float* Wk = (const float*)d_in[2];
  const float* Wv = (const float*)d_in[3];
  const float* Wo = (const float*)d_in[4];
  float* out = (float*)d_out;
  float* ws = (float*)d_ws;

  const size_t B = (size_t)NROWS * D;   // 4,194,304 floats per slot
  float* q_raw = ws + 0 * B;
  float* k_raw = ws + 1 * B;
  float* v_raw = ws + 2 * B;
  float* q_s   = ws + 3 * B;
  float* k_sm  = ws + 4 * B;
  float* kbuf  = ws + 5 * B;
  float* vbuf  = ws + 6 * B;
  float* u     = ws + 7 * B;
  float* w     = ws + 8 * B;
  float* attn  = ws + 9 * B;
  float* wt    = ws + 10 * B;
  float* o_lin = kbuf;

  ushort_t* x_hi = (ushort_t*)u;
  ushort_t* x_lo = (ushort_t*)w;
  ushort_t* Wt_h = (ushort_t*)wt;
  ushort_t* Wt_l = Wt_h + B;
  ushort_t* qb16 = (ushort_t*)q_s;
  ushort_t* kb16 = (ushort_t*)k_sm;
  ushort_t* vt16 = (ushort_t*)vbuf;
  ushort_t* mixh = (ushort_t*)q_raw;
  ushort_t* mixl = (ushort_t*)k_raw;

  dim3 wg(64, 64);

  split_f32<<<4096, 256, 0, stream>>>(x, x_hi, x_lo);
  wsplit_t<<<wg, 256, 0, stream>>>(Wq, Wt_h, Wt_l);
  gemm_split<<<256, 256, 0, stream>>>(x_hi, x_lo, Wt_h, Wt_l, q_raw, NROWS, D, D);
  wsplit_t<<<wg, 256, 0, stream>>>(Wk, Wt_h, Wt_l);
  gemm_split<<<256, 256, 0, stream>>>(x_hi, x_lo, Wt_h, Wt_l, k_raw, NROWS, D, D);
  wsplit_t<<<wg, 256, 0, stream>>>(Wv, Wt_h, Wt_l);
  gemm_split<<<256, 256, 0, stream>>>(x_hi, x_lo, Wt_h, Wt_l, v_raw, NROWS, D, D);

  act_kernel<<<8192, 256, 0, stream>>>(q_raw, k_raw, v_raw, q_s, k_sm, kbuf, vbuf);
  chunk_uw_kernel<<<512, 256, 0, stream>>>(q_s, k_sm, kbuf, vbuf, u, w, attn);
  scan_kernel<<<dim3(32, 8), 512, 0, stream>>>(q_s, k_sm, u, w, attn, o_lin);

  qk_to_bf16<<<4096, 256, 0, stream>>>(q_raw, k_raw, qb16, kb16);
  v_transpose<<<dim3(32, 4, 32), 256, 0, stream>>>(v_raw, vt16);
  attn_mfma<<<dim3(32, 16), 256, 0, stream>>>(qb16, kb16, vt16, o_lin, mixh, mixl);

  wsplit_t<<<wg, 256, 0, stream>>>(Wo, Wt_h, Wt_l);
  gemm_split<<<256, 256, 0, stream>>>(mixh, mixl, Wt_h, Wt_l, out, NROWS, D, D);
}

// Round 5
// 724.343 us; speedup vs baseline: 3.2166x; 1.1736x over previous
//
#include <hip/hip_runtime.h>
#include <hip/hip_bf16.h>
#include <math.h>

#define D 2048
#define NROWS 2048      // b*n
#define H 16
#define DH 128
#define CHK 64
#define NC 16
#define EPSC 1e-6f
#define RSQDH 0.08838834764831845f   // 128^-0.5

typedef unsigned short ushort_t;
typedef __attribute__((ext_vector_type(4))) float f4_t;
typedef __attribute__((ext_vector_type(8))) short s8_t;
typedef __attribute__((ext_vector_type(4))) unsigned short us4_t;

#define MFMA16(a, b, c) __builtin_amdgcn_mfma_f32_16x16x32_bf16((a), (b), (c), 0, 0, 0)
#define GLOAD16(g, l) __builtin_amdgcn_global_load_lds((const __attribute__((address_space(1))) unsigned int*)(g), (__attribute__((address_space(3))) unsigned int*)(l), 16, 0, 0)

__device__ __forceinline__ ushort_t f2bf(float f) {
  union { float f; unsigned u; } v; v.f = f;
  unsigned r = (v.u + 0x7fffu + ((v.u >> 16) & 1u)) >> 16;
  return (ushort_t)r;
}
__device__ __forceinline__ float bf2f(ushort_t h) {
  union { unsigned u; float f; } v; v.u = ((unsigned)h) << 16;
  return v.f;
}

// ---------------- split fp32 -> bf16 hi/lo (elementwise) -------------------
__global__ __launch_bounds__(256) void split_f32(const float* __restrict__ in,
                                                 ushort_t* __restrict__ hi,
                                                 ushort_t* __restrict__ lo) {
  int i = (blockIdx.x * 256 + threadIdx.x) * 4;
  float4 v = *(const float4*)(in + i);
  us4_t h, l;
  float vv[4] = {v.x, v.y, v.z, v.w};
#pragma unroll
  for (int j = 0; j < 4; j++) {
    ushort_t hb = f2bf(vv[j]);
    h[j] = hb;
    l[j] = f2bf(vv[j] - bf2f(hb));
  }
  *(us4_t*)(hi + i) = h;
  *(us4_t*)(lo + i) = l;
}

// ------------- weight: transpose + split -> Wt_hi[n][k], Wt_lo[n][k] -------
__global__ __launch_bounds__(256) void wsplit_t(const float* __restrict__ W,
                                                ushort_t* __restrict__ Th,
                                                ushort_t* __restrict__ Tl) {
  __shared__ float t[32][33];
  const int tid = threadIdx.x;
  const int k0 = blockIdx.y * 32, n0 = blockIdx.x * 32;
  const int c = tid & 31, rr = tid >> 5;
#pragma unroll
  for (int p = 0; p < 4; p++) {
    int r = p * 8 + rr;
    t[r][c] = W[(size_t)(k0 + r) * D + n0 + c];
  }
  __syncthreads();
#pragma unroll
  for (int p = 0; p < 4; p++) {
    int r = p * 8 + rr;                       // output row (n index)
    float v = t[c][r];                        // W[k0+c][n0+r]
    ushort_t hb = f2bf(v);
    Th[(size_t)(n0 + r) * D + k0 + c] = hb;
    Tl[(size_t)(n0 + r) * D + k0 + c] = f2bf(v - bf2f(hb));
  }
}

// ------ split-bf16 MFMA GEMM: C = (Ah+Al)@(Bh+Bl)^T' (3-term, virtual 3K) --
__global__ __launch_bounds__(256) void gemm_split(const ushort_t* __restrict__ Ah,
                                                  const ushort_t* __restrict__ Al,
                                                  const ushort_t* __restrict__ Bth,
                                                  const ushort_t* __restrict__ Btl,
                                                  float* __restrict__ C,
                                                  int M, int N, int K) {
  __shared__ __align__(16) ushort_t As[2][4096];   // [128][32]
  __shared__ __align__(16) ushort_t Bs[2][4096];   // [128 cols][32 k]
  const int tid = threadIdx.x, lane = tid & 63, wid = tid >> 6;
  const int nwg = gridDim.x;
  int bid = blockIdx.x;
  int swz = (bid & 7) * (nwg >> 3) + (bid >> 3);   // XCD swizzle (nwg%8==0)
  const int nbn = N >> 7;
  const int bm = swz / nbn, bn = swz % nbn;
  const int row0 = bm << 7, col0 = bn << 7;
  const int lm = lane & 15, lg = lane >> 4;
  const int wrow = (wid >> 1) * 64, wcol = (wid & 1) * 64;
  const int KSEG = K >> 5;
  const int NT = KSEG * 3;

  f4_t acc[4][4];
#pragma unroll
  for (int m = 0; m < 4; m++)
#pragma unroll
    for (int n = 0; n < 4; n++) acc[m][n] = (f4_t){0.f, 0.f, 0.f, 0.f};

  auto stage = [&](int buf, int t) {
    int seg = t / KSEG;
    int k0 = (t % KSEG) << 5;
    const ushort_t* Ag = (seg == 2) ? Al : Ah;
    const ushort_t* Bg = (seg == 1) ? Btl : Bth;
#pragma unroll
    for (int p = 0; p < 2; p++) {
      int c = p * 256 + wid * 64 + lane;          // chunk 0..511 (16B each)
      const ushort_t* ga = Ag + (size_t)(row0 + (c >> 2)) * K + k0 + (c & 3) * 8;
      char* la = (char*)&As[buf][0] + p * 4096 + wid * 1024;
      GLOAD16(ga, la);
      const ushort_t* gb = Bg + (size_t)(col0 + (c >> 2)) * K + k0 + (c & 3) * 8;
      char* lb = (char*)&Bs[buf][0] + p * 4096 + wid * 1024;
      GLOAD16(gb, lb);
    }
  };

  stage(0, 0);
  __syncthreads();
  for (int t = 0; t < NT; t++) {
    int cur = t & 1;
    if (t + 1 < NT) stage(cur ^ 1, t + 1);
    s8_t af[4], bfr[4];
#pragma unroll
    for (int m = 0; m < 4; m++)
      af[m] = *(const s8_t*)&As[cur][(wrow + m * 16 + lm) * 32 + lg * 8];
#pragma unroll
    for (int n = 0; n < 4; n++)
      bfr[n] = *(const s8_t*)&Bs[cur][(wcol + n * 16 + lm) * 32 + lg * 8];
#pragma unroll
    for (int m = 0; m < 4; m++)
#pragma unroll
      for (int n = 0; n < 4; n++)
        acc[m][n] = MFMA16(af[m], bfr[n], acc[m][n]);
    __syncthreads();
  }
#pragma unroll
  for (int m = 0; m < 4; m++)
#pragma unroll
    for (int n = 0; n < 4; n++)
#pragma unroll
      for (int r = 0; r < 4; r++)
        C[(size_t)(row0 + wrow + m * 16 + lg * 4 + r) * N + col0 + wcol + n * 16 + lm] = acc[m][n][r];
}

// ---------------- activations: softmax/clip q,k ; gate g ; kb, vb ----------
__device__ __forceinline__ float gate_fn(float z) {
  float t = -z;
  float sp = (t > 20.f) ? t : log1pf(expf(t));   // softplus(-z)
  float g = -sp * (1.f / 16.f);                  // log_sigmoid(z)/16
  return fminf(fmaxf(g, -16.f), 16.f);
}

__global__ __launch_bounds__(256) void act_kernel(const float* __restrict__ qr,
                                                  const float* __restrict__ kr,
                                                  const float* __restrict__ vr,
                                                  float* __restrict__ qs,
                                                  float* __restrict__ ksm,
                                                  float* __restrict__ kb,
                                                  float* __restrict__ vb) {
  int wave = blockIdx.x * 4 + (threadIdx.x >> 6);  // (row*16 + h)
  int lane = threadIdx.x & 63;
  size_t base = (size_t)wave * 128;
  float q0 = qr[base + lane], q1 = qr[base + 64 + lane];
  float k0 = kr[base + lane], k1 = kr[base + 64 + lane];
  float v0 = vr[base + lane], v1 = vr[base + 64 + lane];

  float m = fmaxf(q0, q1);
  for (int o = 1; o < 64; o <<= 1) m = fmaxf(m, __shfl_xor(m, o));
  float e0 = expf(q0 - m), e1 = expf(q1 - m);
  float s = e0 + e1;
  for (int o = 1; o < 64; o <<= 1) s += __shfl_xor(s, o);
  float inv = 1.f / s;
  float qs0 = fminf(fmaxf(e0 * inv, EPSC), 1.f - EPSC) * RSQDH;
  float qs1 = fminf(fmaxf(e1 * inv, EPSC), 1.f - EPSC) * RSQDH;

  float mk = fmaxf(k0, k1);
  for (int o = 1; o < 64; o <<= 1) mk = fmaxf(mk, __shfl_xor(mk, o));
  float f0 = expf(k0 - mk), f1 = expf(k1 - mk);
  float sk = f0 + f1;
  for (int o = 1; o < 64; o <<= 1) sk += __shfl_xor(sk, o);
  float invk = 1.f / sk;
  float ks0 = fminf(fmaxf(f0 * invk, EPSC), 1.f - EPSC);
  float ks1 = fminf(fmaxf(f1 * invk, EPSC), 1.f - EPSC);

  float g0 = gate_fn(k0), g1 = gate_fn(k1);

  qs[base + lane] = qs0;        qs[base + 64 + lane] = qs1;
  ksm[base + lane] = ks0;       ksm[base + 64 + lane] = ks1;
  kb[base + lane] = ks0 * g0;   kb[base + 64 + lane] = ks1 * g1;
  vb[base + lane] = v0 * g0;    vb[base + 64 + lane] = v1 * g1;
}

// ------- per-chunk (MFMA): L = kb@k^T, attn = q@k^T, fwd-subst -> u, w -----
// 3-term bf16 hi/lo split MFMA (fp32-level accuracy). In-kernel conversion,
// XOR-swizzled LDS. 3 barriers. LDS = 80KB -> 2 blocks/CU.
__global__ __launch_bounds__(256) void chunk_uw_kernel(const float* __restrict__ qs,
                                                       const float* __restrict__ ksm,
                                                       const float* __restrict__ kb,
                                                       const float* __restrict__ vb,
                                                       float* __restrict__ u,
                                                       float* __restrict__ w,
                                                       float* __restrict__ attn) {
  __shared__ __align__(16) ushort_t kh_s[8192];   // k hi  [64][128] swizzled
  __shared__ __align__(16) ushort_t kl_s[8192];   // k lo
  __shared__ __align__(16) ushort_t xh_s[8192];   // kb hi, then q hi
  __shared__ __align__(16) ushort_t xl_s[8192];   // kb lo, then q lo
  __shared__ float L_s[4096];                     // [64][64]
  const int tid = threadIdx.x, lane = tid & 63, wid = tid >> 6;
  const int lm = lane & 15, lg = lane >> 4;
  const int bh = blockIdx.x >> 4, ci = blockIdx.x & 15;
  const int rowbase = (bh >> 4) * 1024 + ci * 64;
  const int colbase = (bh & 15) * 128;
  const size_t gbase = (size_t)rowbase * D + colbase;
  const int wr = (wid >> 1) * 32, wc = (wid & 1) * 32;   // output quadrant

  // fp32 [64][128] -> hi/lo bf16 swizzled LDS
  auto stageM = [&](const float* __restrict__ src, ushort_t* dh, ushort_t* dl) {
#pragma unroll
    for (int it = 0; it < 4; it++) {
      int idx = tid + it * 256;
      int r = idx >> 4, c8 = idx & 15;
      const float* g = src + gbase + (size_t)r * D + c8 * 8;
      float4 v0 = *(const float4*)g;
      float4 v1 = *(const float4*)(g + 4);
      float vv[8] = {v0.x, v0.y, v0.z, v0.w, v1.x, v1.y, v1.z, v1.w};
      s8_t hv, lv;
#pragma unroll
      for (int j = 0; j < 8; j++) {
        ushort_t hb = f2bf(vv[j]);
        hv[j] = (short)hb;
        lv[j] = (short)f2bf(vv[j] - bf2f(hb));
      }
      int byo = r * 256 + ((c8 * 16) ^ ((r & 7) << 4));
      *(s8_t*)((char*)dh + byo) = hv;
      *(s8_t*)((char*)dl + byo) = lv;
    }
  };

  // 32x32 quadrant of X @ Y^T (3-term split), X rows = out rows, Y rows = cols
  auto mm3 = [&](const ushort_t* Ah, const ushort_t* Al,
                 const ushort_t* Bh, const ushort_t* Bl, f4_t acc[2][2]) {
#pragma unroll
    for (int m = 0; m < 2; m++)
#pragma unroll
      for (int n = 0; n < 2; n++) acc[m][n] = (f4_t){0.f, 0.f, 0.f, 0.f};
#pragma unroll
    for (int term = 0; term < 3; term++) {
      const ushort_t* A = (term == 2) ? Al : Ah;
      const ushort_t* Bsrc = (term == 1) ? Bl : Bh;
#pragma unroll
      for (int ks = 0; ks < 4; ks++) {
        s8_t af[2], bf_[2];
#pragma unroll
        for (int m = 0; m < 2; m++) {
          int row = wr + m * 16 + lm;
          int byo = row * 256 + ((ks * 64 + lg * 16) ^ ((row & 7) << 4));
          af[m] = *(const s8_t*)((const char*)A + byo);
        }
#pragma unroll
        for (int n = 0; n < 2; n++) {
          int row = wc + n * 16 + lm;
          int byo = row * 256 + ((ks * 64 + lg * 16) ^ ((row & 7) << 4));
          bf_[n] = *(const s8_t*)((const char*)Bsrc + byo);
        }
#pragma unroll
        for (int m = 0; m < 2; m++)
#pragma unroll
          for (int n = 0; n < 2; n++)
            acc[m][n] = MFMA16(af[m], bf_[n], acc[m][n]);
      }
    }
  };

  stageM(ksm, kh_s, kl_s);
  stageM(kb, xh_s, xl_s);
  __syncthreads();

  f4_t accL[2][2];
  mm3(xh_s, xl_s, kh_s, kl_s, accL);
#pragma unroll
  for (int m = 0; m < 2; m++)
#pragma unroll
    for (int n = 0; n < 2; n++)
#pragma unroll
      for (int r = 0; r < 4; r++) {
        int i = wr + m * 16 + lg * 4 + r;
        int j = wc + n * 16 + lm;
        L_s[i * 64 + j] = (j < i) ? accL[m][n][r] : 0.f;
      }
  __syncthreads();                 // kb reads done + L_s visible

  stageM(qs, xh_s, xl_s);          // overwrite kb slots with q
  __syncthreads();

  f4_t accA[2][2];
  mm3(xh_s, xl_s, kh_s, kl_s, accA);
  float* ab = attn + (size_t)blockIdx.x * 4096;
#pragma unroll
  for (int m = 0; m < 2; m++)
#pragma unroll
    for (int n = 0; n < 2; n++)
#pragma unroll
      for (int r = 0; r < 4; r++) {
        int i = wr + m * 16 + lg * 4 + r;
        int j = wc + n * 16 + lm;
        ab[i * 64 + j] = (j <= i) ? accA[m][n][r] : 0.f;
      }

  // forward substitution: (I+L) x = rhs; threads 0..127 -> u, 128..255 -> w
  float x[64];
  const int c = tid & 127;
  const float* rhs = (tid < 128) ? (vb + gbase + c) : (kb + gbase + c);
#pragma unroll
  for (int j = 0; j < 64; j++) x[j] = rhs[(size_t)j * D];
#pragma unroll
  for (int i = 0; i < 64; i++) {
    float xi = x[i];
#pragma unroll
    for (int r2 = i + 1; r2 < 64; r2++) x[r2] -= L_s[r2 * 64 + i] * xi;
  }
  float* dst = (tid < 128) ? u : w;
#pragma unroll
  for (int j = 0; j < 64; j++) dst[gbase + (size_t)j * D + c] = x[j];
}

// ------- sequential scan over chunks: grid(32 bh, 8 vgroups), 512 thr ------
__global__ __launch_bounds__(512) void scan_kernel(const float* __restrict__ qs,
                                                   const float* __restrict__ ksm,
                                                   const float* __restrict__ u,
                                                   const float* __restrict__ w,
                                                   const float* __restrict__ attn,
                                                   float* __restrict__ o_lin) {
  __shared__ float w_s[64 * 132];   // +4 pad: per-wave row addrs on distinct banks
  __shared__ float q_s2[64 * 132];
  __shared__ float k_s2[64 * 132];
  __shared__ float a_s[64 * 68];
  __shared__ float S_s[128 * 16];
  __shared__ float u_s[64 * 16];
  const int tid = threadIdx.x;
  const int bh = blockIdx.x;
  const int b = bh >> 4, h = bh & 15;
  const int g = blockIdx.y;            // 0..7 (16 dv cols each)
  const int colbase = h * 128;
  const int vcol = h * 128 + g * 16;
  const int c = tid & 15;
  const int i2 = tid >> 4;             // 0..31
  const int i0 = i2 * 2;               // phase1/2 row pair
  const int k0 = i2 * 4;               // phase3 rows

  for (int i = tid; i < 2048; i += 512) S_s[i] = 0.f;

  for (int chunk = 0; chunk < 16; chunk++) {
    const int rowbase = b * 1024 + chunk * 64;
    const size_t gbase = (size_t)rowbase * D;
#pragma unroll
    for (int it = 0; it < 4; it++) {
      int f4 = tid + it * 512;           // 0..2047
      int r = f4 >> 5, c4 = (f4 & 31) * 4;
      float4 wv = *(const float4*)(w + gbase + (size_t)r * D + colbase + c4);
      *(float4*)&w_s[r * 132 + c4] = wv;
      float4 qv = *(const float4*)(qs + gbase + (size_t)r * D + colbase + c4);
      *(float4*)&q_s2[r * 132 + c4] = qv;
      float4 kv = *(const float4*)(ksm + gbase + (size_t)r * D + colbase + c4);
      *(float4*)&k_s2[r * 132 + c4] = kv;
    }
    const float* ab = attn + (size_t)(bh * 16 + chunk) * 4096;
#pragma unroll
    for (int it = 0; it < 2; it++) {
      int f4 = tid + it * 512;           // 0..1023
      int r = f4 >> 4, c4 = (f4 & 15) * 4;
      float4 av = *(const float4*)(ab + r * 64 + c4);
      *(float4*)&a_s[r * 68 + c4] = av;
    }
    float u0 = u[gbase + (size_t)i0 * D + vcol + c];
    float u1 = u[gbase + (size_t)(i0 + 1) * D + vcol + c];
    __syncthreads();                     // A: staging + S_s update visible
    float a0 = 0.f, a1 = 0.f;
    for (int k = 0; k < 128; k++) {
      float sv = S_s[k * 16 + c];
      a0 += w_s[i0 * 132 + k] * sv;
      a1 += w_s[(i0 + 1) * 132 + k] * sv;
    }
    u_s[i0 * 16 + c] = u0 - a0;
    u_s[(i0 + 1) * 16 + c] = u1 - a1;
    __syncthreads();                     // B: u' visible
    float o0 = 0.f, o1 = 0.f;
    for (int k = 0; k < 128; k++) {
      float sv = S_s[k * 16 + c];
      o0 += q_s2[i0 * 132 + k] * sv;
      o1 += q_s2[(i0 + 1) * 132 + k] * sv;
    }
    for (int j = 0; j < 64; j++) {
      float uv = u_s[j * 16 + c];
      o0 += a_s[i0 * 68 + j] * uv;
      o1 += a_s[(i0 + 1) * 68 + j] * uv;
    }
    o_lin[gbase + (size_t)i0 * D + vcol + c] = o0;
    o_lin[gbase + (size_t)(i0 + 1) * D + vcol + c] = o1;
    float s3[4] = {0.f, 0.f, 0.f, 0.f};
    for (int i = 0; i < 64; i++) {
      float uv = u_s[i * 16 + c];
#pragma unroll
      for (int r = 0; r < 4; r++) s3[r] += k_s2[i * 132 + k0 + r] * uv;
    }
    __syncthreads();                     // C: all shared reads done
#pragma unroll
    for (int r = 0; r < 4; r++) S_s[(k0 + r) * 16 + c] += s3[r];
  }
}

// -------- q,k -> bf16 (q pre-scaled by 1/sqrt(DH)) ------------------------
__global__ __launch_bounds__(256) void qk_to_bf16(const float* __restrict__ qr,
                                                  const float* __restrict__ kr,
                                                  ushort_t* __restrict__ qb,
                                                  ushort_t* __restrict__ kbf) {
  int i = (blockIdx.x * 256 + threadIdx.x) * 4;
  float4 q = *(const float4*)(qr + i);
  float4 k = *(const float4*)(kr + i);
  us4_t qo, ko;
  float qq[4] = {q.x, q.y, q.z, q.w}, kk2[4] = {k.x, k.y, k.z, k.w};
#pragma unroll
  for (int j = 0; j < 4; j++) {
    qo[j] = f2bf(qq[j] * RSQDH);
    ko[j] = f2bf(kk2[j]);
  }
  *(us4_t*)(qb + i) = qo;
  *(us4_t*)(kbf + i) = ko;
}

// -------- v -> transposed bf16 vt[b][h][d][n] -----------------------------
__global__ __launch_bounds__(256) void v_transpose(const float* __restrict__ vr,
                                                   ushort_t* __restrict__ vt) {
  __shared__ float t[32][33];
  const int tid = threadIdx.x;
  const int n0 = blockIdx.x * 32;      // 32 tiles
  const int d0 = blockIdx.y * 32;      // 4 tiles
  const int bh = blockIdx.z;           // 32
  const int b = bh >> 4, h = bh & 15;
  const int c = tid & 31, rr = tid >> 5;
#pragma unroll
  for (int p = 0; p < 4; p++) {
    int r = p * 8 + rr;
    t[r][c] = vr[(size_t)(b * 1024 + n0 + r) * D + h * 128 + d0 + c];
  }
  __syncthreads();
#pragma unroll
  for (int p = 0; p < 4; p++) {
    int r = p * 8 + rr;                // d offset
    vt[(size_t)(bh * 128 + d0 + r) * 1024 + n0 + c] = f2bf(t[c][r]);
  }
}

// -------- MFMA bf16 flash attention + 0.5/0.5 mix + bf16-split out --------
__global__ __launch_bounds__(256) void attn_mfma(const ushort_t* __restrict__ qb,
                                                 const ushort_t* __restrict__ kb,
                                                 const ushort_t* __restrict__ vt,
                                                 const float* __restrict__ o_lin,
                                                 ushort_t* __restrict__ mixh,
                                                 ushort_t* __restrict__ mixl) {
  __shared__ __align__(16) ushort_t K_s[8192];    // [64 keys][128 d] swizzled
  __shared__ __align__(16) ushort_t V_s[8192];    // [128 d][64 keys] swizzled
  __shared__ __align__(16) ushort_t P_s[4][1152]; // per-wave [16][72]
  const int tid = threadIdx.x;
  const int lane = tid & 63, wid = tid >> 6;
  const int bh = blockIdx.x;
  const int b = bh >> 4, h = bh & 15;
  const int qt = blockIdx.y;
  const int lm = lane & 15, lg = lane >> 4;

  s8_t qf[4];
  const size_t qrowG = (size_t)(b * 1024 + qt * 64 + wid * 16 + lm);
#pragma unroll
  for (int kb4 = 0; kb4 < 4; kb4++)
    qf[kb4] = *(const s8_t*)(qb + qrowG * D + h * 128 + kb4 * 32 + lg * 8);

  f4_t o[8];
#pragma unroll
  for (int n = 0; n < 8; n++) o[n] = (f4_t){0.f, 0.f, 0.f, 0.f};
  float mrow[4] = {-INFINITY, -INFINITY, -INFINITY, -INFINITY};
  float lrow[4] = {0.f, 0.f, 0.f, 0.f};
  const int myq = qt * 64 + wid * 16 + lg * 4;   // + r

  for (int kt = 0; kt <= qt; kt++) {
    __syncthreads();
#pragma unroll
    for (int p = 0; p < 4; p++) {
      int c = tid + p * 256;
      int key = c >> 4, dc = c & 15;
      s8_t v = *(const s8_t*)(kb + (size_t)(b * 1024 + kt * 64 + key) * D + h * 128 + dc * 8);
      int byo = key * 256 + ((dc * 16) ^ ((key & 7) << 4));
      *(s8_t*)((char*)K_s + byo) = v;
    }
#pragma unroll
    for (int p = 0; p < 4; p++) {
      int c = tid + p * 256;
      int d = c >> 3, nc = c & 7;
      s8_t v = *(const s8_t*)(vt + (size_t)(bh * 128 + d) * 1024 + kt * 64 + nc * 8);
      int byo = d * 128 + ((nc * 16) ^ ((d & 7) << 4));
      *(s8_t*)((char*)V_s + byo) = v;
    }
    __syncthreads();

    f4_t s[4];
#pragma unroll
    for (int ks = 0; ks < 4; ks++) {
      f4_t a = (f4_t){0.f, 0.f, 0.f, 0.f};
      int key = ks * 16 + lm;
#pragma unroll
      for (int kb4 = 0; kb4 < 4; kb4++) {
        int byo = key * 256 + ((kb4 * 64 + lg * 16) ^ ((key & 7) << 4));
        s8_t kf = *(const s8_t*)((char*)K_s + byo);
        a = MFMA16(qf[kb4], kf, a);
      }
      s[ks] = a;
    }
    if (kt == qt) {
#pragma unroll
      for (int ks = 0; ks < 4; ks++) {
        int key = kt * 64 + ks * 16 + lm;
#pragma unroll
        for (int r = 0; r < 4; r++)
          if (key > myq + r) s[ks][r] = -INFINITY;
      }
    }
    float mloc[4];
#pragma unroll
    for (int r = 0; r < 4; r++) {
      mloc[r] = fmaxf(fmaxf(s[0][r], s[1][r]), fmaxf(s[2][r], s[3][r]));
      mloc[r] = fmaxf(mloc[r], __shfl_xor(mloc[r], 1));
      mloc[r] = fmaxf(mloc[r], __shfl_xor(mloc[r], 2));
      mloc[r] = fmaxf(mloc[r], __shfl_xor(mloc[r], 4));
      mloc[r] = fmaxf(mloc[r], __shfl_xor(mloc[r], 8));
    }
    float scale[4];
#pragma unroll
    for (int r = 0; r < 4; r++) {
      float mn = fmaxf(mrow[r], mloc[r]);
      scale[r] = __expf(mrow[r] - mn);
      mrow[r] = mn;
    }
    float lad[4] = {0.f, 0.f, 0.f, 0.f};
#pragma unroll
    for (int ks = 0; ks < 4; ks++)
#pragma unroll
      for (int r = 0; r < 4; r++) {
        float p = __expf(s[ks][r] - mrow[r]);
        lad[r] += p;
        P_s[wid][(lg * 4 + r) * 72 + ks * 16 + lm] = f2bf(p);
      }
#pragma unroll
    for (int r = 0; r < 4; r++) {
      lad[r] += __shfl_xor(lad[r], 1);
      lad[r] += __shfl_xor(lad[r], 2);
      lad[r] += __shfl_xor(lad[r], 4);
      lad[r] += __shfl_xor(lad[r], 8);
      lrow[r] = lrow[r] * scale[r] + lad[r];
    }
#pragma unroll
    for (int n = 0; n < 8; n++)
#pragma unroll
      for (int r = 0; r < 4; r++) o[n][r] *= scale[r];

    s8_t pf[2];
#pragma unroll
    for (int ksl = 0; ksl < 2; ksl++)
      pf[ksl] = *(const s8_t*)&P_s[wid][lm * 72 + ksl * 32 + lg * 8];
#pragma unroll
    for (int n = 0; n < 8; n++) {
      int d = n * 16 + lm;
#pragma unroll
      for (int ksl = 0; ksl < 2; ksl++) {
        int byo = d * 128 + ((ksl * 64 + lg * 16) ^ ((d & 7) << 4));
        s8_t vf = *(const s8_t*)((char*)V_s + byo);
        o[n] = MFMA16(pf[ksl], vf, o[n]);
      }
    }
  }

  float invl[4];
#pragma unroll
  for (int r = 0; r < 4; r++) invl[r] = 1.f / lrow[r];
#pragma unroll
  for (int n = 0; n < 8; n++)
#pragma unroll
    for (int r = 0; r < 4; r++) {
      size_t G = (size_t)(b * 1024 + qt * 64 + wid * 16 + lg * 4 + r);
      int dcol = h * 128 + n * 16 + lm;
      float mix = 0.5f * (o[n][r] * invl[r]) + 0.5f * o_lin[G * D + dcol];
      ushort_t hb = f2bf(mix);
      mixh[G * D + dcol] = hb;
      mixl[G * D + dcol] = f2bf(mix - bf2f(hb));
    }
}

// ---------------------------------------------------------------------------
extern "C" void kernel_launch(void* const* d_in, const int* in_sizes, int n_in,
                              void* d_out, int out_size, void* d_ws, size_t ws_size,
                              hipStream_t stream) {
  const float* x  = (const float*)d_in[0];
  const float* Wq = (const float*)d_in[1];
  const float* Wk = (const float*)d_in[2];
  const float* Wv = (const float*)d_in[3];
  const float* Wo = (const float*)d_in[4];
  float* out = (float*)d_out;
  float* ws = (float*)d_ws;

  const size_t B = (size_t)NROWS * D;   // 4,194,304 floats per slot
  float* q_raw = ws + 0 * B;
  float* k_raw = ws + 1 * B;
  float* v_raw = ws + 2 * B;
  float* q_s   = ws + 3 * B;
  float* k_sm  = ws + 4 * B;
  float* kbuf  = ws + 5 * B;
  float* vbuf  = ws + 6 * B;
  float* u     = ws + 7 * B;
  float* w     = ws + 8 * B;
  float* attn  = ws + 9 * B;
  float* wt    = ws + 10 * B;
  float* o_lin = kbuf;

  ushort_t* x_hi = (ushort_t*)u;
  ushort_t* x_lo = (ushort_t*)w;
  ushort_t* Wt_h = (ushort_t*)wt;
  ushort_t* Wt_l = Wt_h + B;
  ushort_t* qb16 = (ushort_t*)q_s;
  ushort_t* kb16 = (ushort_t*)k_sm;
  ushort_t* vt16 = (ushort_t*)vbuf;
  ushort_t* mixh = (ushort_t*)q_raw;
  ushort_t* mixl = (ushort_t*)k_raw;

  dim3 wg(64, 64);

  split_f32<<<4096, 256, 0, stream>>>(x, x_hi, x_lo);
  wsplit_t<<<wg, 256, 0, stream>>>(Wq, Wt_h, Wt_l);
  gemm_split<<<256, 256, 0, stream>>>(x_hi, x_lo, Wt_h, Wt_l, q_raw, NROWS, D, D);
  wsplit_t<<<wg, 256, 0, stream>>>(Wk, Wt_h, Wt_l);
  gemm_split<<<256, 256, 0, stream>>>(x_hi, x_lo, Wt_h, Wt_l, k_raw, NROWS, D, D);
  wsplit_t<<<wg, 256, 0, stream>>>(Wv, Wt_h, Wt_l);
  gemm_split<<<256, 256, 0, stream>>>(x_hi, x_lo, Wt_h, Wt_l, v_raw, NROWS, D, D);

  act_kernel<<<8192, 256, 0, stream>>>(q_raw, k_raw, v_raw, q_s, k_sm, kbuf, vbuf);
  chunk_uw_kernel<<<512, 256, 0, stream>>>(q_s, k_sm, kbuf, vbuf, u, w, attn);
  scan_kernel<<<dim3(32, 8), 512, 0, stream>>>(q_s, k_sm, u, w, attn, o_lin);

  qk_to_bf16<<<4096, 256, 0, stream>>>(q_raw, k_raw, qb16, kb16);
  v_transpose<<<dim3(32, 4, 32), 256, 0, stream>>>(v_raw, vt16);
  attn_mfma<<<dim3(32, 16), 256, 0, stream>>>(qb16, kb16, vt16, o_lin, mixh, mixl);

  wsplit_t<<<wg, 256, 0, stream>>>(Wo, Wt_h, Wt_l);
  gemm_split<<<256, 256, 0, stream>>>(mixh, mixl, Wt_h, Wt_l, out, NROWS, D, D);
}

// Round 6
// 471.821 us; speedup vs baseline: 4.9381x; 1.5352x over previous
//
#include <hip/hip_runtime.h>
#include <hip/hip_bf16.h>
#include <math.h>

#define D 2048
#define NROWS 2048      // b*n
#define NQKV 6144       // fused QKV width
#define H 16
#define DH 128
#define CHK 64
#define NC 16
#define EPSC 1e-6f
#define RSQDH 0.08838834764831845f   // 128^-0.5

typedef unsigned short ushort_t;
typedef __attribute__((ext_vector_type(4))) float f4_t;
typedef __attribute__((ext_vector_type(8))) short s8_t;
typedef __attribute__((ext_vector_type(8))) _Float16 h8_t;
typedef __attribute__((ext_vector_type(4))) _Float16 h4_t;
typedef __attribute__((ext_vector_type(4))) unsigned short us4_t;

#define MFMA16(a, b, c) __builtin_amdgcn_mfma_f32_16x16x32_bf16((a), (b), (c), 0, 0, 0)
#define MFMAH(a, b, c)  __builtin_amdgcn_mfma_f32_16x16x32_f16((a), (b), (c), 0, 0, 0)
#define GLOAD16(g, l) __builtin_amdgcn_global_load_lds((const __attribute__((address_space(1))) unsigned int*)(g), (__attribute__((address_space(3))) unsigned int*)(l), 16, 0, 0)

__device__ __forceinline__ ushort_t f2bf(float f) {
  union { float f; unsigned u; } v; v.f = f;
  unsigned r = (v.u + 0x7fffu + ((v.u >> 16) & 1u)) >> 16;
  return (ushort_t)r;
}
__device__ __forceinline__ float bf2f(ushort_t h) {
  union { unsigned u; float f; } v; v.u = ((unsigned)h) << 16;
  return v.f;
}

// ---------------- split fp32 -> fp16 hi/lo (elementwise) -------------------
__global__ __launch_bounds__(256) void split16(const float* __restrict__ in,
                                               _Float16* __restrict__ hi,
                                               _Float16* __restrict__ lo) {
  int i = (blockIdx.x * 256 + threadIdx.x) * 4;
  float4 v = *(const float4*)(in + i);
  float vv[4] = {v.x, v.y, v.z, v.w};
  h4_t h, l;
#pragma unroll
  for (int j = 0; j < 4; j++) {
    _Float16 hb = (_Float16)vv[j];
    h[j] = hb;
    l[j] = (_Float16)(vv[j] - (float)hb);
  }
  *(h4_t*)(hi + i) = h;
  *(h4_t*)(lo + i) = l;
}

// ------------- weight: transpose + fp16 round -> T[n][k] -------------------
__global__ __launch_bounds__(256) void wsplit_h(const float* __restrict__ W,
                                                _Float16* __restrict__ T) {
  __shared__ float t[32][33];
  const int tid = threadIdx.x;
  const int k0 = blockIdx.y * 32, n0 = blockIdx.x * 32;
  const int c = tid & 31, rr = tid >> 5;
#pragma unroll
  for (int p = 0; p < 4; p++) {
    int r = p * 8 + rr;
    t[r][c] = W[(size_t)(k0 + r) * D + n0 + c];
  }
  __syncthreads();
#pragma unroll
  for (int p = 0; p < 4; p++) {
    int r = p * 8 + rr;
    T[(size_t)(n0 + r) * D + k0 + c] = (_Float16)t[c][r];
  }
}

// ------ fp16 2-term MFMA GEMM: C = (Ah+Al) @ Bt^T, B fragments shared ------
// A hi/lo: [M][K] fp16 row-major. Bt: [N][K] fp16 (transposed weights).
__global__ __launch_bounds__(256) void gemm2(const _Float16* __restrict__ Ah,
                                             const _Float16* __restrict__ Al,
                                             const _Float16* __restrict__ Bt,
                                             float* __restrict__ C,
                                             int M, int N, int K) {
  __shared__ __align__(16) ushort_t Ah_s[2][4096];   // [128][32]
  __shared__ __align__(16) ushort_t Al_s[2][4096];
  __shared__ __align__(16) ushort_t B_s[2][4096];    // [128 cols][32 k]
  const int tid = threadIdx.x, lane = tid & 63, wid = tid >> 6;
  const int nwg = gridDim.x;
  int bid = blockIdx.x;
  int swz = (bid & 7) * (nwg >> 3) + (bid >> 3);     // XCD swizzle (nwg%8==0)
  const int nbn = N >> 7;
  const int bm = swz / nbn, bn = swz % nbn;
  const int row0 = bm << 7, col0 = bn << 7;
  const int lm = lane & 15, lg = lane >> 4;
  const int wrow = (wid >> 1) * 64, wcol = (wid & 1) * 64;
  const int NT = K >> 5;

  f4_t acc[4][4];
#pragma unroll
  for (int m = 0; m < 4; m++)
#pragma unroll
    for (int n = 0; n < 4; n++) acc[m][n] = (f4_t){0.f, 0.f, 0.f, 0.f};

  auto stage = [&](int buf, int ks) {
    int k0 = ks << 5;
#pragma unroll
    for (int p = 0; p < 2; p++) {
      int c = p * 256 + wid * 64 + lane;             // 16B chunk 0..511
      int r = c >> 2, q = (c & 3) * 8;
      char* la = (char*)&Ah_s[buf][0] + p * 4096 + wid * 1024;
      GLOAD16(Ah + (size_t)(row0 + r) * K + k0 + q, la);
      char* ll = (char*)&Al_s[buf][0] + p * 4096 + wid * 1024;
      GLOAD16(Al + (size_t)(row0 + r) * K + k0 + q, ll);
      char* lb = (char*)&B_s[buf][0] + p * 4096 + wid * 1024;
      GLOAD16(Bt + (size_t)(col0 + r) * K + k0 + q, lb);
    }
  };

  stage(0, 0);
  __syncthreads();
  for (int t = 0; t < NT; t++) {
    int cur = t & 1;
    if (t + 1 < NT) stage(cur ^ 1, t + 1);
    h8_t afh[4], afl[4], bfr[4];
#pragma unroll
    for (int m = 0; m < 4; m++) {
      afh[m] = *(const h8_t*)&Ah_s[cur][(wrow + m * 16 + lm) * 32 + lg * 8];
      afl[m] = *(const h8_t*)&Al_s[cur][(wrow + m * 16 + lm) * 32 + lg * 8];
    }
#pragma unroll
    for (int n = 0; n < 4; n++)
      bfr[n] = *(const h8_t*)&B_s[cur][(wcol + n * 16 + lm) * 32 + lg * 8];
#pragma unroll
    for (int m = 0; m < 4; m++)
#pragma unroll
      for (int n = 0; n < 4; n++) {
        acc[m][n] = MFMAH(afh[m], bfr[n], acc[m][n]);
        acc[m][n] = MFMAH(afl[m], bfr[n], acc[m][n]);
      }
    __syncthreads();
  }
#pragma unroll
  for (int m = 0; m < 4; m++)
#pragma unroll
    for (int n = 0; n < 4; n++)
#pragma unroll
      for (int r = 0; r < 4; r++)
        C[(size_t)(row0 + wrow + m * 16 + lg * 4 + r) * N + col0 + wcol + n * 16 + lm] = acc[m][n][r];
}

// ---------------- activations: softmax/clip q,k ; gate g ; kb, vb ----------
__device__ __forceinline__ float gate_fn(float z) {
  float t = -z;
  float sp = (t > 20.f) ? t : log1pf(expf(t));   // softplus(-z)
  float g = -sp * (1.f / 16.f);                  // log_sigmoid(z)/16
  return fminf(fmaxf(g, -16.f), 16.f);
}

__global__ __launch_bounds__(256) void act_kernel(const float* __restrict__ qkv,
                                                  float* __restrict__ qs,
                                                  float* __restrict__ ksm,
                                                  float* __restrict__ kb,
                                                  float* __restrict__ vb) {
  int wave = blockIdx.x * 4 + (threadIdx.x >> 6);  // (row*16 + h)
  int lane = threadIdx.x & 63;
  int row = wave >> 4, h = wave & 15;
  size_t inb = (size_t)row * NQKV + h * 128;
  size_t base = (size_t)wave * 128;
  float q0 = qkv[inb + lane],        q1 = qkv[inb + 64 + lane];
  float k0 = qkv[inb + 2048 + lane], k1 = qkv[inb + 2048 + 64 + lane];
  float v0 = qkv[inb + 4096 + lane], v1 = qkv[inb + 4096 + 64 + lane];

  float m = fmaxf(q0, q1);
  for (int o = 1; o < 64; o <<= 1) m = fmaxf(m, __shfl_xor(m, o));
  float e0 = expf(q0 - m), e1 = expf(q1 - m);
  float s = e0 + e1;
  for (int o = 1; o < 64; o <<= 1) s += __shfl_xor(s, o);
  float inv = 1.f / s;
  float qs0 = fminf(fmaxf(e0 * inv, EPSC), 1.f - EPSC) * RSQDH;
  float qs1 = fminf(fmaxf(e1 * inv, EPSC), 1.f - EPSC) * RSQDH;

  float mk = fmaxf(k0, k1);
  for (int o = 1; o < 64; o <<= 1) mk = fmaxf(mk, __shfl_xor(mk, o));
  float f0 = expf(k0 - mk), f1 = expf(k1 - mk);
  float sk = f0 + f1;
  for (int o = 1; o < 64; o <<= 1) sk += __shfl_xor(sk, o);
  float invk = 1.f / sk;
  float ks0 = fminf(fmaxf(f0 * invk, EPSC), 1.f - EPSC);
  float ks1 = fminf(fmaxf(f1 * invk, EPSC), 1.f - EPSC);

  float g0 = gate_fn(k0), g1 = gate_fn(k1);

  qs[base + lane] = qs0;        qs[base + 64 + lane] = qs1;
  ksm[base + lane] = ks0;       ksm[base + 64 + lane] = ks1;
  kb[base + lane] = ks0 * g0;   kb[base + 64 + lane] = ks1 * g1;
  vb[base + lane] = v0 * g0;    vb[base + 64 + lane] = v1 * g1;
}

// ------- per-chunk (MFMA): L = kb@k^T, attn = q@k^T, fwd-subst -> u, w -----
__global__ __launch_bounds__(256) void chunk_uw_kernel(const float* __restrict__ qs,
                                                       const float* __restrict__ ksm,
                                                       const float* __restrict__ kb,
                                                       const float* __restrict__ vb,
                                                       float* __restrict__ u,
                                                       float* __restrict__ w,
                                                       float* __restrict__ attn) {
  __shared__ __align__(16) ushort_t kh_s[8192];   // k hi  [64][128] swizzled
  __shared__ __align__(16) ushort_t kl_s[8192];   // k lo
  __shared__ __align__(16) ushort_t xh_s[8192];   // kb hi, then q hi
  __shared__ __align__(16) ushort_t xl_s[8192];   // kb lo, then q lo
  __shared__ float L_s[4096];                     // [64][64]
  const int tid = threadIdx.x, lane = tid & 63, wid = tid >> 6;
  const int lm = lane & 15, lg = lane >> 4;
  const int bh = blockIdx.x >> 4, ci = blockIdx.x & 15;
  const int rowbase = (bh >> 4) * 1024 + ci * 64;
  const int colbase = (bh & 15) * 128;
  const size_t gbase = (size_t)rowbase * D + colbase;
  const int wr = (wid >> 1) * 32, wc = (wid & 1) * 32;

  auto stageM = [&](const float* __restrict__ src, ushort_t* dh, ushort_t* dl) {
#pragma unroll
    for (int it = 0; it < 4; it++) {
      int idx = tid + it * 256;
      int r = idx >> 4, c8 = idx & 15;
      const float* g = src + gbase + (size_t)r * D + c8 * 8;
      float4 v0 = *(const float4*)g;
      float4 v1 = *(const float4*)(g + 4);
      float vv[8] = {v0.x, v0.y, v0.z, v0.w, v1.x, v1.y, v1.z, v1.w};
      s8_t hv, lv;
#pragma unroll
      for (int j = 0; j < 8; j++) {
        ushort_t hb = f2bf(vv[j]);
        hv[j] = (short)hb;
        lv[j] = (short)f2bf(vv[j] - bf2f(hb));
      }
      int byo = r * 256 + ((c8 * 16) ^ ((r & 7) << 4));
      *(s8_t*)((char*)dh + byo) = hv;
      *(s8_t*)((char*)dl + byo) = lv;
    }
  };

  auto mm3 = [&](const ushort_t* Ah, const ushort_t* Al,
                 const ushort_t* Bh, const ushort_t* Bl, f4_t acc[2][2]) {
#pragma unroll
    for (int m = 0; m < 2; m++)
#pragma unroll
      for (int n = 0; n < 2; n++) acc[m][n] = (f4_t){0.f, 0.f, 0.f, 0.f};
#pragma unroll
    for (int term = 0; term < 3; term++) {
      const ushort_t* A = (term == 2) ? Al : Ah;
      const ushort_t* Bsrc = (term == 1) ? Bl : Bh;
#pragma unroll
      for (int ks = 0; ks < 4; ks++) {
        s8_t af[2], bf_[2];
#pragma unroll
        for (int m = 0; m < 2; m++) {
          int row = wr + m * 16 + lm;
          int byo = row * 256 + ((ks * 64 + lg * 16) ^ ((row & 7) << 4));
          af[m] = *(const s8_t*)((const char*)A + byo);
        }
#pragma unroll
        for (int n = 0; n < 2; n++) {
          int row = wc + n * 16 + lm;
          int byo = row * 256 + ((ks * 64 + lg * 16) ^ ((row & 7) << 4));
          bf_[n] = *(const s8_t*)((const char*)Bsrc + byo);
        }
#pragma unroll
        for (int m = 0; m < 2; m++)
#pragma unroll
          for (int n = 0; n < 2; n++)
            acc[m][n] = MFMA16(af[m], bf_[n], acc[m][n]);
      }
    }
  };

  stageM(ksm, kh_s, kl_s);
  stageM(kb, xh_s, xl_s);
  __syncthreads();

  f4_t accL[2][2];
  mm3(xh_s, xl_s, kh_s, kl_s, accL);
#pragma unroll
  for (int m = 0; m < 2; m++)
#pragma unroll
    for (int n = 0; n < 2; n++)
#pragma unroll
      for (int r = 0; r < 4; r++) {
        int i = wr + m * 16 + lg * 4 + r;
        int j = wc + n * 16 + lm;
        L_s[i * 64 + j] = (j < i) ? accL[m][n][r] : 0.f;
      }
  __syncthreads();

  stageM(qs, xh_s, xl_s);
  __syncthreads();

  f4_t accA[2][2];
  mm3(xh_s, xl_s, kh_s, kl_s, accA);
  float* ab = attn + (size_t)blockIdx.x * 4096;
#pragma unroll
  for (int m = 0; m < 2; m++)
#pragma unroll
    for (int n = 0; n < 2; n++)
#pragma unroll
      for (int r = 0; r < 4; r++) {
        int i = wr + m * 16 + lg * 4 + r;
        int j = wc + n * 16 + lm;
        ab[i * 64 + j] = (j <= i) ? accA[m][n][r] : 0.f;
      }

  float x[64];
  const int c = tid & 127;
  const float* rhs = (tid < 128) ? (vb + gbase + c) : (kb + gbase + c);
#pragma unroll
  for (int j = 0; j < 64; j++) x[j] = rhs[(size_t)j * D];
#pragma unroll
  for (int i = 0; i < 64; i++) {
    float xi = x[i];
#pragma unroll
    for (int r2 = i + 1; r2 < 64; r2++) x[r2] -= L_s[r2 * 64 + i] * xi;
  }
  float* dst = (tid < 128) ? u : w;
#pragma unroll
  for (int j = 0; j < 64; j++) dst[gbase + (size_t)j * D + c] = x[j];
}

// ------- sequential scan over chunks: grid(32 bh, 8 vgroups), 512 thr ------
__global__ __launch_bounds__(512) void scan_kernel(const float* __restrict__ qs,
                                                   const float* __restrict__ ksm,
                                                   const float* __restrict__ u,
                                                   const float* __restrict__ w,
                                                   const float* __restrict__ attn,
                                                   float* __restrict__ o_lin) {
  __shared__ float w_s[64 * 132];
  __shared__ float q_s2[64 * 132];
  __shared__ float k_s2[64 * 132];
  __shared__ float a_s[64 * 68];
  __shared__ float S_s[128 * 16];
  __shared__ float u_s[64 * 16];
  const int tid = threadIdx.x;
  const int bh = blockIdx.x;
  const int b = bh >> 4, h = bh & 15;
  const int g = blockIdx.y;
  const int colbase = h * 128;
  const int vcol = h * 128 + g * 16;
  const int c = tid & 15;
  const int i2 = tid >> 4;
  const int i0 = i2 * 2;
  const int k0 = i2 * 4;

  for (int i = tid; i < 2048; i += 512) S_s[i] = 0.f;

  for (int chunk = 0; chunk < 16; chunk++) {
    const int rowbase = b * 1024 + chunk * 64;
    const size_t gbase = (size_t)rowbase * D;
#pragma unroll
    for (int it = 0; it < 4; it++) {
      int f4 = tid + it * 512;
      int r = f4 >> 5, c4 = (f4 & 31) * 4;
      float4 wv = *(const float4*)(w + gbase + (size_t)r * D + colbase + c4);
      *(float4*)&w_s[r * 132 + c4] = wv;
      float4 qv = *(const float4*)(qs + gbase + (size_t)r * D + colbase + c4);
      *(float4*)&q_s2[r * 132 + c4] = qv;
      float4 kv = *(const float4*)(ksm + gbase + (size_t)r * D + colbase + c4);
      *(float4*)&k_s2[r * 132 + c4] = kv;
    }
    const float* ab = attn + (size_t)(bh * 16 + chunk) * 4096;
#pragma unroll
    for (int it = 0; it < 2; it++) {
      int f4 = tid + it * 512;
      int r = f4 >> 4, c4 = (f4 & 15) * 4;
      float4 av = *(const float4*)(ab + r * 64 + c4);
      *(float4*)&a_s[r * 68 + c4] = av;
    }
    float u0 = u[gbase + (size_t)i0 * D + vcol + c];
    float u1 = u[gbase + (size_t)(i0 + 1) * D + vcol + c];
    __syncthreads();
    float a0 = 0.f, a1 = 0.f;
    for (int k = 0; k < 128; k++) {
      float sv = S_s[k * 16 + c];
      a0 += w_s[i0 * 132 + k] * sv;
      a1 += w_s[(i0 + 1) * 132 + k] * sv;
    }
    u_s[i0 * 16 + c] = u0 - a0;
    u_s[(i0 + 1) * 16 + c] = u1 - a1;
    __syncthreads();
    float o0 = 0.f, o1 = 0.f;
    for (int k = 0; k < 128; k++) {
      float sv = S_s[k * 16 + c];
      o0 += q_s2[i0 * 132 + k] * sv;
      o1 += q_s2[(i0 + 1) * 132 + k] * sv;
    }
    for (int j = 0; j < 64; j++) {
      float uv = u_s[j * 16 + c];
      o0 += a_s[i0 * 68 + j] * uv;
      o1 += a_s[(i0 + 1) * 68 + j] * uv;
    }
    o_lin[gbase + (size_t)i0 * D + vcol + c] = o0;
    o_lin[gbase + (size_t)(i0 + 1) * D + vcol + c] = o1;
    float s3[4] = {0.f, 0.f, 0.f, 0.f};
    for (int i = 0; i < 64; i++) {
      float uv = u_s[i * 16 + c];
#pragma unroll
      for (int r = 0; r < 4; r++) s3[r] += k_s2[i * 132 + k0 + r] * uv;
    }
    __syncthreads();
#pragma unroll
    for (int r = 0; r < 4; r++) S_s[(k0 + r) * 16 + c] += s3[r];
  }
}

// -------- q,k -> bf16 from fused qkv (q pre-scaled by 1/sqrt(DH)) ---------
__global__ __launch_bounds__(256) void qk_to_bf16(const float* __restrict__ qkv,
                                                  ushort_t* __restrict__ qb,
                                                  ushort_t* __restrict__ kbf) {
  int i = (blockIdx.x * 256 + threadIdx.x) * 4;
  int row = i >> 11, col = i & 2047;
  size_t src = (size_t)row * NQKV + col;
  float4 q = *(const float4*)(qkv + src);
  float4 k = *(const float4*)(qkv + src + 2048);
  us4_t qo, ko;
  float qq[4] = {q.x, q.y, q.z, q.w}, kk2[4] = {k.x, k.y, k.z, k.w};
#pragma unroll
  for (int j = 0; j < 4; j++) {
    qo[j] = f2bf(qq[j] * RSQDH);
    ko[j] = f2bf(kk2[j]);
  }
  *(us4_t*)(qb + i) = qo;
  *(us4_t*)(kbf + i) = ko;
}

// -------- v (from qkv) -> transposed bf16 vt[b][h][d][n] ------------------
__global__ __launch_bounds__(256) void v_transpose(const float* __restrict__ qkv,
                                                   ushort_t* __restrict__ vt) {
  __shared__ float t[32][33];
  const int tid = threadIdx.x;
  const int n0 = blockIdx.x * 32;
  const int d0 = blockIdx.y * 32;
  const int bh = blockIdx.z;
  const int b = bh >> 4, h = bh & 15;
  const int c = tid & 31, rr = tid >> 5;
#pragma unroll
  for (int p = 0; p < 4; p++) {
    int r = p * 8 + rr;
    t[r][c] = qkv[(size_t)(b * 1024 + n0 + r) * NQKV + 4096 + h * 128 + d0 + c];
  }
  __syncthreads();
#pragma unroll
  for (int p = 0; p < 4; p++) {
    int r = p * 8 + rr;
    vt[(size_t)(bh * 128 + d0 + r) * 1024 + n0 + c] = f2bf(t[c][r]);
  }
}

// -------- MFMA bf16 flash attention + 0.5/0.5 mix + fp16-split out --------
__global__ __launch_bounds__(256) void attn_mfma(const ushort_t* __restrict__ qb,
                                                 const ushort_t* __restrict__ kb,
                                                 const ushort_t* __restrict__ vt,
                                                 const float* __restrict__ o_lin,
                                                 _Float16* __restrict__ mixh,
                                                 _Float16* __restrict__ mixl) {
  __shared__ __align__(16) ushort_t K_s[8192];
  __shared__ __align__(16) ushort_t V_s[8192];
  __shared__ __align__(16) ushort_t P_s[4][1152];
  const int tid = threadIdx.x;
  const int lane = tid & 63, wid = tid >> 6;
  const int bh = blockIdx.x;
  const int b = bh >> 4, h = bh & 15;
  const int qt = blockIdx.y;
  const int lm = lane & 15, lg = lane >> 4;

  s8_t qf[4];
  const size_t qrowG = (size_t)(b * 1024 + qt * 64 + wid * 16 + lm);
#pragma unroll
  for (int kb4 = 0; kb4 < 4; kb4++)
    qf[kb4] = *(const s8_t*)(qb + qrowG * D + h * 128 + kb4 * 32 + lg * 8);

  f4_t o[8];
#pragma unroll
  for (int n = 0; n < 8; n++) o[n] = (f4_t){0.f, 0.f, 0.f, 0.f};
  float mrow[4] = {-INFINITY, -INFINITY, -INFINITY, -INFINITY};
  float lrow[4] = {0.f, 0.f, 0.f, 0.f};
  const int myq = qt * 64 + wid * 16 + lg * 4;

  for (int kt = 0; kt <= qt; kt++) {
    __syncthreads();
#pragma unroll
    for (int p = 0; p < 4; p++) {
      int c = tid + p * 256;
      int key = c >> 4, dc = c & 15;
      s8_t v = *(const s8_t*)(kb + (size_t)(b * 1024 + kt * 64 + key) * D + h * 128 + dc * 8);
      int byo = key * 256 + ((dc * 16) ^ ((key & 7) << 4));
      *(s8_t*)((char*)K_s + byo) = v;
    }
#pragma unroll
    for (int p = 0; p < 4; p++) {
      int c = tid + p * 256;
      int d = c >> 3, nc = c & 7;
      s8_t v = *(const s8_t*)(vt + (size_t)(bh * 128 + d) * 1024 + kt * 64 + nc * 8);
      int byo = d * 128 + ((nc * 16) ^ ((d & 7) << 4));
      *(s8_t*)((char*)V_s + byo) = v;
    }
    __syncthreads();

    f4_t s[4];
#pragma unroll
    for (int ks = 0; ks < 4; ks++) {
      f4_t a = (f4_t){0.f, 0.f, 0.f, 0.f};
      int key = ks * 16 + lm;
#pragma unroll
      for (int kb4 = 0; kb4 < 4; kb4++) {
        int byo = key * 256 + ((kb4 * 64 + lg * 16) ^ ((key & 7) << 4));
        s8_t kf = *(const s8_t*)((char*)K_s + byo);
        a = MFMA16(qf[kb4], kf, a);
      }
      s[ks] = a;
    }
    if (kt == qt) {
#pragma unroll
      for (int ks = 0; ks < 4; ks++) {
        int key = kt * 64 + ks * 16 + lm;
#pragma unroll
        for (int r = 0; r < 4; r++)
          if (key > myq + r) s[ks][r] = -INFINITY;
      }
    }
    float mloc[4];
#pragma unroll
    for (int r = 0; r < 4; r++) {
      mloc[r] = fmaxf(fmaxf(s[0][r], s[1][r]), fmaxf(s[2][r], s[3][r]));
      mloc[r] = fmaxf(mloc[r], __shfl_xor(mloc[r], 1));
      mloc[r] = fmaxf(mloc[r], __shfl_xor(mloc[r], 2));
      mloc[r] = fmaxf(mloc[r], __shfl_xor(mloc[r], 4));
      mloc[r] = fmaxf(mloc[r], __shfl_xor(mloc[r], 8));
    }
    float scale[4];
#pragma unroll
    for (int r = 0; r < 4; r++) {
      float mn = fmaxf(mrow[r], mloc[r]);
      scale[r] = __expf(mrow[r] - mn);
      mrow[r] = mn;
    }
    float lad[4] = {0.f, 0.f, 0.f, 0.f};
#pragma unroll
    for (int ks = 0; ks < 4; ks++)
#pragma unroll
      for (int r = 0; r < 4; r++) {
        float p = __expf(s[ks][r] - mrow[r]);
        lad[r] += p;
        P_s[wid][(lg * 4 + r) * 72 + ks * 16 + lm] = f2bf(p);
      }
#pragma unroll
    for (int r = 0; r < 4; r++) {
      lad[r] += __shfl_xor(lad[r], 1);
      lad[r] += __shfl_xor(lad[r], 2);
      lad[r] += __shfl_xor(lad[r], 4);
      lad[r] += __shfl_xor(lad[r], 8);
      lrow[r] = lrow[r] * scale[r] + lad[r];
    }
#pragma unroll
    for (int n = 0; n < 8; n++)
#pragma unroll
      for (int r = 0; r < 4; r++) o[n][r] *= scale[r];

    s8_t pf[2];
#pragma unroll
    for (int ksl = 0; ksl < 2; ksl++)
      pf[ksl] = *(const s8_t*)&P_s[wid][lm * 72 + ksl * 32 + lg * 8];
#pragma unroll
    for (int n = 0; n < 8; n++) {
      int d = n * 16 + lm;
#pragma unroll
      for (int ksl = 0; ksl < 2; ksl++) {
        int byo = d * 128 + ((ksl * 64 + lg * 16) ^ ((d & 7) << 4));
        s8_t vf = *(const s8_t*)((char*)V_s + byo);
        o[n] = MFMA16(pf[ksl], vf, o[n]);
      }
    }
  }

  float invl[4];
#pragma unroll
  for (int r = 0; r < 4; r++) invl[r] = 1.f / lrow[r];
#pragma unroll
  for (int n = 0; n < 8; n++)
#pragma unroll
    for (int r = 0; r < 4; r++) {
      size_t G = (size_t)(b * 1024 + qt * 64 + wid * 16 + lg * 4 + r);
      int dcol = h * 128 + n * 16 + lm;
      float mix = 0.5f * (o[n][r] * invl[r]) + 0.5f * o_lin[G * D + dcol];
      _Float16 hb = (_Float16)mix;
      mixh[G * D + dcol] = hb;
      mixl[G * D + dcol] = (_Float16)(mix - (float)hb);
    }
}

// ---------------------------------------------------------------------------
extern "C" void kernel_launch(void* const* d_in, const int* in_sizes, int n_in,
                              void* d_out, int out_size, void* d_ws, size_t ws_size,
                              hipStream_t stream) {
  const float* x  = (const float*)d_in[0];
  const float* Wq = (const float*)d_in[1];
  const float* Wk = (const float*)d_in[2];
  const float* Wv = (const float*)d_in[3];
  const float* Wo = (const float*)d_in[4];
  float* out = (float*)d_out;
  float* ws = (float*)d_ws;

  const size_t B = (size_t)NROWS * D;   // 4,194,304 floats per slot
  float* qkv  = ws + 0 * B;             // slots 0-2: [2048][6144] fp32
  float* q_s  = ws + 3 * B;             // -> qb16 later
  float* k_sm = ws + 4 * B;             // -> kb16 later
  float* kbuf = ws + 5 * B;             // -> o_lin
  float* vbuf = ws + 6 * B;             // -> vt16
  float* u    = ws + 7 * B;             // x_hi/x_lo first
  float* w    = ws + 8 * B;
  float* attn = ws + 9 * B;             // 2M floats; time-shares with Wt
  float* o_lin = kbuf;

  _Float16* x_hi = (_Float16*)u;                    // 4M halfs
  _Float16* x_lo = x_hi + B;                        // 4M halfs (same slot)
  _Float16* Wt   = (_Float16*)(ws + 9 * B);         // 3*D*D halfs (25MB, slots 9-10)
  _Float16* Wo_t = Wt;                              // 8MB, after attn consumed
  ushort_t* qb16 = (ushort_t*)q_s;
  ushort_t* kb16 = (ushort_t*)k_sm;
  ushort_t* vt16 = (ushort_t*)vbuf;
  _Float16* mixh = (_Float16*)qkv;                  // reuse q region
  _Float16* mixl = mixh + B;

  dim3 wg(64, 64);

  split16<<<4096, 256, 0, stream>>>(x, x_hi, x_lo);
  wsplit_h<<<wg, 256, 0, stream>>>(Wq, Wt + 0 * B);
  wsplit_h<<<wg, 256, 0, stream>>>(Wk, Wt + 1 * B);
  wsplit_h<<<wg, 256, 0, stream>>>(Wv, Wt + 2 * B);
  gemm2<<<16 * 48, 256, 0, stream>>>(x_hi, x_lo, Wt, qkv, NROWS, NQKV, D);

  act_kernel<<<8192, 256, 0, stream>>>(qkv, q_s, k_sm, kbuf, vbuf);
  chunk_uw_kernel<<<512, 256, 0, stream>>>(q_s, k_sm, kbuf, vbuf, u, w, attn);
  scan_kernel<<<dim3(32, 8), 512, 0, stream>>>(q_s, k_sm, u, w, attn, o_lin);

  qk_to_bf16<<<4096, 256, 0, stream>>>(qkv, qb16, kb16);
  v_transpose<<<dim3(32, 4, 32), 256, 0, stream>>>(qkv, vt16);
  attn_mfma<<<dim3(32, 16), 256, 0, stream>>>(qb16, kb16, vt16, o_lin, mixh, mixl);

  wsplit_h<<<wg, 256, 0, stream>>>(Wo, Wo_t);
  gemm2<<<16 * 16, 256, 0, stream>>>(mixh, mixl, Wo_t, out, NROWS, D, D);
}